// Round 1
// baseline (859.898 us; speedup 1.0000x reference)
//
#include <hip/hip_runtime.h>
#include <math.h>

namespace {

constexpr int N_ = 8, C_ = 256, S_ = 64, HW_ = 256;
constexpr int NS = N_ * S_;      // 512 columns (n,s)
constexpr int NHW = N_ * HW_;    // 2048 columns (n,hw)

// ---- workspace layout (float offsets) ----
constexpr size_t SZ_DESC = (size_t)NS * C_;           // 131072
constexpr size_t O_DESC = 0;
constexpr size_t O_DN   = O_DESC + SZ_DESC;
constexpr size_t SZ_MIC = (size_t)N_ * 768 * 80;      // padded rows of 80
constexpr size_t O_MIC  = O_DN + SZ_DESC;
constexpr size_t SZ_MPRE = (size_t)3 * 4 * 2048 * 64; // [conv][icpart][n*256+o][s]
constexpr size_t O_MPRE = O_MIC + SZ_MIC;
constexpr size_t O_MSUM = O_MPRE + SZ_MPRE;
constexpr size_t O_MOT  = O_MSUM + SZ_DESC;
constexpr size_t SZ_GIB = (size_t)NS * 512;
constexpr size_t O_GIB  = O_MOT + SZ_DESC;
constexpr size_t O_GATE = O_GIB + SZ_GIB;
constexpr size_t SZ_MOI = (size_t)NS * 768;
constexpr size_t O_MOI  = O_GATE + SZ_DESC;
constexpr size_t O_HMO  = O_MOI + SZ_MOI;
constexpr size_t O_MEM  = O_HMO + SZ_DESC;
constexpr size_t O_PPIN = O_MEM + SZ_DESC;
constexpr size_t O_PHASE= O_PPIN + SZ_DESC;
constexpr size_t O_FGATE= O_PHASE + SZ_DESC;
constexpr size_t SZ_BPI = (size_t)NS * 1024;
constexpr size_t O_BPI  = O_FGATE + SZ_DESC;
constexpr size_t O_HBP  = O_BPI + SZ_BPI;
constexpr size_t O_DELTA= O_HBP + SZ_DESC;
constexpr size_t SZ_SPT = (size_t)NHW * C_;
constexpr size_t O_SPT  = O_DELTA + SZ_DESC;
constexpr size_t O_SGATE= O_SPT + SZ_SPT;
constexpr size_t O_FE   = O_SGATE + SZ_SPT;   // 264 used, 512 reserved
constexpr size_t O_MFRE = O_FE + 512;
constexpr size_t O_MFIM = O_MFRE + 512;
constexpr size_t O_PK   = O_MFIM + 512;       // [n][4]: conf, pnorm, dphase, ang
constexpr size_t O_BW   = O_PK + 32;          // [n][3]
constexpr size_t SZ_WT3 = (size_t)768*3*256;
constexpr size_t O_WT3  = O_BW + 32;
constexpr size_t SZ_WT5 = (size_t)768*5*256;
constexpr size_t O_WT5  = O_WT3 + SZ_WT3;
constexpr size_t SZ_WT7 = (size_t)768*7*256;
constexpr size_t O_WT7  = O_WT5 + SZ_WT5;
constexpr size_t O_ATMF = O_WT7 + SZ_WT7;
constexpr size_t O_ATMG = O_ATMF + 256*256;
constexpr size_t O_ATMO1= O_ATMG + 512*256;
constexpr size_t O_ATMO2= O_ATMO1 + 768*256;
constexpr size_t O_ATPP = O_ATMO2 + 256*256;
constexpr size_t O_ATBP1= O_ATPP + 256*256;
constexpr size_t O_ATBP2= O_ATBP1 + 1024*256;
constexpr size_t O_ATFG = O_ATBP2 + 256*256;
constexpr size_t O_ATSG = O_ATFG + 256*256;

__device__ __forceinline__ float gelu_f(float v) {
  return 0.5f * v * (1.0f + erff(v * 0.70710678118654752f));
}
__device__ __forceinline__ float sigmoid_f(float v) {
  return 1.0f / (1.0f + expf(-v));
}

// block (256 threads) sum with broadcast; scratch = 4 floats in LDS
__device__ __forceinline__ float block_sum256(float v, float* scratch) {
  #pragma unroll
  for (int off = 32; off; off >>= 1) v += __shfl_down(v, off, 64);
  int w = threadIdx.x >> 6;
  __syncthreads();
  if ((threadIdx.x & 63) == 0) scratch[w] = v;
  __syncthreads();
  return scratch[0] + scratch[1] + scratch[2] + scratch[3];
}

// ---------------- weight repack (transpose) ----------------
__global__ __launch_bounds__(256) void prep_weights_kernel(
    const float* __restrict__ w3, const float* __restrict__ w5, const float* __restrict__ w7,
    const float* __restrict__ wmf, const float* __restrict__ wmg,
    const float* __restrict__ wmo1, const float* __restrict__ wmo2,
    const float* __restrict__ wpp, const float* __restrict__ wbp1,
    const float* __restrict__ wbp2, const float* __restrict__ wfg,
    const float* __restrict__ wsg, float* __restrict__ ws) {
  long long id = (long long)blockIdx.x * 256 + threadIdx.x;
  if (id < (long long)SZ_WT3) {
    int o = (int)(id & 255); long long r = id >> 8; int dk = (int)(r % 3); int ic = (int)(r / 3);
    ws[O_WT3 + id] = w3[((long long)o * 768 + ic) * 3 + dk]; return;
  }
  id -= SZ_WT3;
  if (id < (long long)SZ_WT5) {
    int o = (int)(id & 255); long long r = id >> 8; int dk = (int)(r % 5); int ic = (int)(r / 5);
    ws[O_WT5 + id] = w5[((long long)o * 768 + ic) * 5 + dk]; return;
  }
  id -= SZ_WT5;
  if (id < (long long)SZ_WT7) {
    int o = (int)(id & 255); long long r = id >> 8; int dk = (int)(r % 7); int ic = (int)(r / 7);
    ws[O_WT7 + id] = w7[((long long)o * 768 + ic) * 7 + dk]; return;
  }
  id -= SZ_WT7;
  if (id < 256*256) { int o=(int)(id&255); int kk=(int)(id>>8); ws[O_ATMF+id] = wmf[o*256+kk]; return; }
  id -= 256*256;
  if (id < 512*256) { int o=(int)(id&255); int kk=(int)(id>>8); ws[O_ATMG+id] = wmg[o*512+kk]; return; }
  id -= 512*256;
  if (id < 768*256) { int o=(int)(id&255); int kk=(int)(id>>8); ws[O_ATMO1+id] = wmo1[o*768+kk]; return; }
  id -= 768*256;
  if (id < 256*256) { int o=(int)(id&255); int kk=(int)(id>>8); ws[O_ATMO2+id] = wmo2[o*256+kk]; return; }
  id -= 256*256;
  if (id < 256*256) { int o=(int)(id&255); int kk=(int)(id>>8); ws[O_ATPP+id] = wpp[o*256+kk]; return; }
  id -= 256*256;
  if (id < 1024*256){ int o=(int)(id&255); int kk=(int)(id>>8); ws[O_ATBP1+id] = wbp1[o*1024+kk]; return; }
  id -= 1024*256;
  if (id < 256*256) { int o=(int)(id&255); int kk=(int)(id>>8); ws[O_ATBP2+id] = wbp2[o*256+kk]; return; }
  id -= 256*256;
  if (id < 256*256) { int o=(int)(id&255); int kk=(int)(id>>8); ws[O_ATFG+id] = wfg[o*256+kk]; return; }
  id -= 256*256;
  if (id < 256*256) { int o=(int)(id&255); int kk=(int)(id>>8); ws[O_ATSG+id] = wsg[o*256+kk]; return; }
}

// ---------------- pass 1: x reductions ----------------
// block = (n,c); desc_t[(n*64+s)*256+c] = mean_{hw} x; sp_t[(n*256+hw)*256+c] = mean_s x
__global__ __launch_bounds__(256) void reduce_x_kernel(
    const float* __restrict__ x, float* __restrict__ desc_t, float* __restrict__ sp_t) {
  int nc = blockIdx.x; int n = nc >> 8; int c = nc & 255;
  int t = threadIdx.x; int w = t >> 6; int l = t & 63;
  const float4* x4 = (const float4*)x + (size_t)nc * 4096;
  float4 sa = {0.f, 0.f, 0.f, 0.f};
  for (int i = 0; i < 16; ++i) {
    int s = w * 16 + i;
    float4 v = x4[(size_t)s * 64 + l];
    sa.x += v.x; sa.y += v.y; sa.z += v.z; sa.w += v.w;
    float ds = v.x + v.y + v.z + v.w;
    #pragma unroll
    for (int off = 32; off; off >>= 1) ds += __shfl_down(ds, off, 64);
    if (l == 0) desc_t[((size_t)n * 64 + s) * 256 + c] = ds * (1.f / 256.f);
  }
  __shared__ float4 lsp[4][64];
  lsp[w][l] = sa;
  __syncthreads();
  if (t < 64) {
    float4 a = lsp[0][t], b = lsp[1][t], c2 = lsp[2][t], d = lsp[3][t];
    float4 tot;
    tot.x = a.x + b.x + c2.x + d.x; tot.y = a.y + b.y + c2.y + d.y;
    tot.z = a.z + b.z + c2.z + d.z; tot.w = a.w + b.w + c2.w + d.w;
    size_t base = ((size_t)n * 256 + t * 4) * 256 + c;
    sp_t[base]       = tot.x * (1.f / 64.f);
    sp_t[base + 256] = tot.y * (1.f / 64.f);
    sp_t[base + 512] = tot.z * (1.f / 64.f);
    sp_t[base + 768] = tot.w * (1.f / 64.f);
  }
}

// ---------------- LayerNorm over C per (n,s) ----------------
__global__ __launch_bounds__(256) void ln_kernel(
    const float* __restrict__ desc_t, const float* __restrict__ g,
    const float* __restrict__ b, float* __restrict__ dn_t) {
  __shared__ float sc[4];
  int col = blockIdx.x; int t = threadIdx.x;
  float v = desc_t[(size_t)col * 256 + t];
  float s1 = block_sum256(v, sc);
  float s2 = block_sum256(v * v, sc);
  float mu = s1 * (1.f / 256.f);
  float var = s2 * (1.f / 256.f) - mu * mu;
  float r = rsqrtf(var + 1e-5f);
  dn_t[(size_t)col * 256 + t] = (v - mu) * r * g[t] + b[t];
}

// ---------------- diffs + staging buffers ----------------
__global__ __launch_bounds__(256) void prep_mi_kernel(
    const float* __restrict__ dn_t, float* __restrict__ mi_c,
    float* __restrict__ gib, float* __restrict__ moi, float* __restrict__ bpi) {
  int col = blockIdx.x; int c = threadIdx.x;
  int n = col >> 6, s = col & 63;
  float d = dn_t[(size_t)col * 256 + c];
  float d1 = (s >= 1) ? d - dn_t[(size_t)(col - 1) * 256 + c] : 0.f;
  float d2 = (s >= 2) ? d - dn_t[(size_t)(col - 2) * 256 + c] : 0.f;
  size_t r0 = ((size_t)n * 768 + c) * 80;
  size_t r1 = ((size_t)n * 768 + 256 + c) * 80;
  size_t r2 = ((size_t)n * 768 + 512 + c) * 80;
  mi_c[r0 + 8 + s] = d; mi_c[r1 + 8 + s] = d1; mi_c[r2 + 8 + s] = d2;
  if (s < 8)  { mi_c[r0 + s] = 0.f; mi_c[r1 + s] = 0.f; mi_c[r2 + s] = 0.f; }
  if (s >= 56){ int p = 72 + (s - 56); mi_c[r0 + p] = 0.f; mi_c[r1 + p] = 0.f; mi_c[r2 + p] = 0.f; }
  gib[(size_t)col * 512 + c] = d;
  gib[(size_t)col * 512 + 256 + c] = fabsf(d1);
  moi[(size_t)col * 768 + c] = d;
  bpi[(size_t)col * 1024 + c] = d;
}

// ---------------- rFFT over S (direct DFT) ----------------
__global__ __launch_bounds__(256) void fft_kernel(
    const float* __restrict__ dn_t, float* __restrict__ fe,
    float* __restrict__ mfre, float* __restrict__ mfim) {
  int b = blockIdx.x; int n = b / 33; int f = b % 33;
  int t = threadIdx.x;
  __shared__ float cs[64], sn[64];
  __shared__ float sc[4];
  if (t < 64) {
    int ft = (f * t) & 63;
    float ang = -6.283185307179586f * (float)ft * (1.f / 64.f);
    cs[t] = cosf(ang); sn[t] = sinf(ang);
  }
  __syncthreads();
  float re = 0.f, im = 0.f;
  const float* base = dn_t + (size_t)n * 16384 + t;
  for (int s = 0; s < 64; ++s) {
    float v = base[(size_t)s * 256];
    re += v * cs[s]; im += v * sn[s];
  }
  re *= 0.125f; im *= 0.125f;   // ortho 1/sqrt(64)
  float mag = sqrtf(re * re + im * im);
  float sm = block_sum256(mag, sc);
  float sr = block_sum256(re, sc);
  float si = block_sum256(im, sc);
  if (t == 0) {
    fe[b]   = sm * (1.f / 256.f);
    mfre[b] = sr * (1.f / 256.f);
    mfim[b] = si * (1.f / 256.f);
  }
}

// ---------------- peak / phase params per n ----------------
__global__ __launch_bounds__(64) void peak_kernel(
    const float* __restrict__ fe, const float* __restrict__ mfre,
    const float* __restrict__ mfim, float* __restrict__ pk) {
  int n = blockIdx.x; int t = threadIdx.x;
  float v = (t < 26) ? fe[n * 33 + 7 + t] : -1e30f;
  int idx = t;
  float hs = (t < 26) ? v : 0.f;
  #pragma unroll
  for (int off = 32; off; off >>= 1) {
    float ov = __shfl_down(v, off, 64);
    int   oi = __shfl_down(idx, off, 64);
    float oh = __shfl_down(hs, off, 64);
    hs += oh;
    if (ov > v || (ov == v && oi < idx)) { v = ov; idx = oi; }
  }
  if (t == 0) {
    int pi = idx + 7;
    float conf = v / fmaxf(hs, 1e-6f);
    float pnorm = (float)pi * (1.f / 32.f);
    float re = mfre[n * 33 + pi], im = mfim[n * 33 + pi];
    float dph = atan2f(im, re);
    float ang = (6.283185307179586f / 64.f) * (float)pi;
    pk[n * 4 + 0] = conf; pk[n * 4 + 1] = pnorm; pk[n * 4 + 2] = dph; pk[n * 4 + 3] = ang;
  }
}

// ---------------- motion convs (k = 3/5/7), ic-split partials ----------------
template <int KS>
__global__ __launch_bounds__(256) void conv_mb_kernel(
    const float* __restrict__ mi_c, const float* __restrict__ wt, float* __restrict__ mpre) {
  int n = blockIdx.x, ot = blockIdx.y, part = blockIdx.z;
  int t = threadIdx.x;
  int o = ot * 32 + (t & 31);
  int s0 = (t >> 5) * 8;
  constexpr int OFF = KS / 2;
  float acc[8];
  #pragma unroll
  for (int j = 0; j < 8; ++j) acc[j] = 0.f;
  int ic0 = part * 192;
  for (int ic = ic0; ic < ic0 + 192; ++ic) {
    const float* row = mi_c + ((size_t)n * 768 + ic) * 80 + 8 + s0 - OFF;
    float win[8 + KS - 1];
    #pragma unroll
    for (int j = 0; j < 8 + KS - 1; ++j) win[j] = row[j];
    const float* wp = wt + ((size_t)ic * KS) * 256 + o;
    #pragma unroll
    for (int dk = 0; dk < KS; ++dk) {
      float w = wp[(size_t)dk * 256];
      #pragma unroll
      for (int j = 0; j < 8; ++j) acc[j] += w * win[dk + j];
    }
  }
  float* outp = mpre + ((size_t)part * 2048 + n * 256 + o) * 64 + s0;
  #pragma unroll
  for (int j = 0; j < 8; ++j) outp[j] = acc[j];
}

// ---------------- combine partials: gelu(bn) sum over 3 convs, /3 ----------------
__global__ __launch_bounds__(256) void combine_kernel(
    const float* __restrict__ mpre,
    const float* __restrict__ s3, const float* __restrict__ b3,
    const float* __restrict__ s5, const float* __restrict__ b5,
    const float* __restrict__ s7, const float* __restrict__ b7,
    float* __restrict__ msum) {
  int id = blockIdx.x * 256 + threadIdx.x;
  int s = id & 63; int o = (id >> 6) & 255; int n = id >> 14;
  size_t base = ((size_t)n * 256 + o) * 64 + s;
  float v0 = mpre[base] + mpre[base + 131072] + mpre[base + 262144] + mpre[base + 393216];
  size_t b5o = base + 524288;
  float v1 = mpre[b5o] + mpre[b5o + 131072] + mpre[b5o + 262144] + mpre[b5o + 393216];
  size_t b7o = base + 1048576;
  float v2 = mpre[b7o] + mpre[b7o + 131072] + mpre[b7o + 262144] + mpre[b7o + 393216];
  float tot = gelu_f(v0 * s3[o] + b3[o]) + gelu_f(v1 * s5[o] + b5[o]) + gelu_f(v2 * s7[o] + b7[o]);
  msum[((size_t)n * 64 + s) * 256 + o] = tot * (1.f / 3.f);
}

// ---------------- generic 1x1-conv GEMM: out_t[col][o] = epi(sum_k At[k][o]*B[col][k]) ----------------
// EPI: 0 = gelu(v*sc+bi); 1 = sigmoid(v+bi); 2 = none; 3 = v*fg[col][o]*rs[o]; 4 = sigmoid(v*sc+bi)
template <int K, int EPI>
__global__ __launch_bounds__(256) void gemm_kernel(
    const float* __restrict__ At, const float* __restrict__ B, float* __restrict__ out,
    const float* __restrict__ sc, const float* __restrict__ bi,
    const float* __restrict__ fg, const float* __restrict__ rs) {
  int t = threadIdx.x;
  int o = blockIdx.x * 64 + (t & 63);
  int c0 = blockIdx.y * 8 + (t >> 6) * 2;
  const float* b0p = B + (size_t)c0 * K;
  const float* b1p = b0p + K;
  float4 a0 = {0.f,0.f,0.f,0.f}, a1 = {0.f,0.f,0.f,0.f};
  for (int kk = 0; kk < K; kk += 4) {
    float4 b0 = *(const float4*)(b0p + kk);
    float4 b1 = *(const float4*)(b1p + kk);
    float w0 = At[(size_t)(kk + 0) * 256 + o];
    float w1 = At[(size_t)(kk + 1) * 256 + o];
    float w2 = At[(size_t)(kk + 2) * 256 + o];
    float w3 = At[(size_t)(kk + 3) * 256 + o];
    a0.x += w0 * b0.x; a0.y += w1 * b0.y; a0.z += w2 * b0.z; a0.w += w3 * b0.w;
    a1.x += w0 * b1.x; a1.y += w1 * b1.y; a1.z += w2 * b1.z; a1.w += w3 * b1.w;
  }
  float v0 = (a0.x + a0.y) + (a0.z + a0.w);
  float v1 = (a1.x + a1.y) + (a1.z + a1.w);
  if constexpr (EPI == 0) { v0 = gelu_f(v0 * sc[o] + bi[o]); v1 = gelu_f(v1 * sc[o] + bi[o]); }
  else if constexpr (EPI == 1) { v0 = sigmoid_f(v0 + bi[o]); v1 = sigmoid_f(v1 + bi[o]); }
  else if constexpr (EPI == 3) {
    v0 *= fg[(size_t)c0 * 256 + o] * rs[o];
    v1 *= fg[(size_t)(c0 + 1) * 256 + o] * rs[o];
  }
  else if constexpr (EPI == 4) { v0 = sigmoid_f(v0 * sc[o] + bi[o]); v1 = sigmoid_f(v1 * sc[o] + bi[o]); }
  out[(size_t)c0 * 256 + o] = v0;
  out[(size_t)(c0 + 1) * 256 + o] = v1;
}

// ---------------- gated fwd/bwd scan over S ----------------
__global__ __launch_bounds__(256) void scan_kernel(
    const float* __restrict__ dn_t, const float* __restrict__ gate_t, float* __restrict__ moi) {
  int n = blockIdx.x; int c = threadIdx.x;
  size_t nb = (size_t)n * 64;
  float st = dn_t[nb * 256 + c];
  moi[nb * 768 + 256 + c] = st;
  for (int s = 1; s < 64; ++s) {
    float g = gate_t[(nb + s) * 256 + c];
    float d = dn_t[(nb + s) * 256 + c];
    st = g * st + (1.f - g) * d;
    moi[(nb + s) * 768 + 256 + c] = st;
  }
  st = dn_t[(nb + 63) * 256 + c];
  moi[(nb + 63) * 768 + 512 + c] = st;
  for (int s = 62; s >= 0; --s) {
    float g = gate_t[(nb + s) * 256 + c];
    float d = dn_t[(nb + s) * 256 + c];
    st = g * st + (1.f - g) * d;
    moi[(nb + s) * 768 + 512 + c] = st;
  }
}

// ---------------- phase gate: pf -> 64 hidden -> pgate; ppin = dn*pgate ----------------
__global__ __launch_bounds__(256) void pgate_kernel(
    const float* __restrict__ dn_t, const float* __restrict__ pk,
    const float* __restrict__ pg_w1, const float* __restrict__ pg_s1, const float* __restrict__ pg_b1,
    const float* __restrict__ pg_w2, const float* __restrict__ pg_b2, float* __restrict__ ppin) {
  int col = blockIdx.x; int n = col >> 6; int s = col & 63;
  int t = threadIdx.x;
  __shared__ float h[64];
  float conf = pk[n * 4 + 0], dph = pk[n * 4 + 2], ang = pk[n * 4 + 3];
  float arg = ang * (float)s + dph;
  float pc = cosf(arg), ps = sinf(arg);
  if (t < 64) {
    float v = pg_w1[t * 3 + 0] * pc + pg_w1[t * 3 + 1] * ps + pg_w1[t * 3 + 2] * conf;
    v = v * pg_s1[t] + pg_b1[t];
    h[t] = gelu_f(v);
  }
  __syncthreads();
  float acc = pg_b2[t];
  const float* wrow = pg_w2 + t * 64;
  #pragma unroll 8
  for (int j = 0; j < 64; ++j) acc += wrow[j] * h[j];
  float pg = sigmoid_f(acc);
  ppin[(size_t)col * 256 + t] = dn_t[(size_t)col * 256 + t] * pg;
}

// ---------------- router: stats + 2-layer MLP + softmax ----------------
__global__ __launch_bounds__(256) void router_kernel(
    const float* __restrict__ dn_t, const float* __restrict__ motion_t,
    const float* __restrict__ memory_t, const float* __restrict__ pk,
    const float* __restrict__ rt_w1, const float* __restrict__ rt_b1,
    const float* __restrict__ rt_w2, const float* __restrict__ rt_b2,
    float* __restrict__ bw) {
  int n = blockIdx.x; int c = threadIdx.x;
  __shared__ float ri[261];
  __shared__ float h2[64];
  __shared__ float lg[3];
  __shared__ float sc[4];
  float sum = 0.f, sq = 0.f, ad1 = 0.f, amot = 0.f, amem = 0.f, prev = 0.f;
  for (int s = 0; s < 64; ++s) {
    size_t i = ((size_t)n * 64 + s) * 256 + c;
    float d = dn_t[i];
    sum += d; sq += d * d;
    if (s > 0) ad1 += fabsf(d - prev);
    prev = d;
    amot += fabsf(motion_t[i]);
    amem += fabsf(memory_t[i] - d);
  }
  float mean = sum * (1.f / 64.f);
  float var = sq * (1.f / 64.f) - mean * mean;
  float stdc = sqrtf(fmaxf(var, 0.f));
  ri[c] = mean;
  float rstd = block_sum256(stdc, sc);
  float rad1 = block_sum256(ad1, sc);
  float rmot = block_sum256(amot, sc);
  float rmem = block_sum256(amem, sc);
  if (c == 0) {
    ri[256] = rstd * (1.f / 256.f);
    ri[257] = rad1 * (1.f / 16384.f);
    ri[258] = pk[n * 4 + 0];
    ri[259] = pk[n * 4 + 1];
    ri[260] = (rmem + rmot) * (1.f / 16384.f);
  }
  __syncthreads();
  if (c < 64) {
    float acc = rt_b1[c];
    const float* wrow = rt_w1 + c * 261;
    for (int i = 0; i < 261; ++i) acc += wrow[i] * ri[i];
    h2[c] = gelu_f(acc);
  }
  __syncthreads();
  if (c < 3) {
    float acc = rt_b2[c];
    const float* wrow = rt_w2 + c * 64;
    #pragma unroll 8
    for (int j = 0; j < 64; ++j) acc += wrow[j] * h2[j];
    lg[c] = acc;
  }
  __syncthreads();
  if (c == 0) {
    float m = fmaxf(lg[0], fmaxf(lg[1], lg[2]));
    float e0 = expf(lg[0] - m), e1 = expf(lg[1] - m), e2 = expf(lg[2] - m);
    float inv = 1.f / (e0 + e1 + e2);
    bw[n * 3 + 0] = e0 * inv; bw[n * 3 + 1] = e1 * inv; bw[n * 3 + 2] = e2 * inv;
  }
}

// ---------------- build bp input rows 256..1023 ----------------
__global__ __launch_bounds__(256) void bp_prep_kernel(
    const float* __restrict__ motion_t, const float* __restrict__ phase_t,
    const float* __restrict__ memory_t, const float* __restrict__ dn_t,
    const float* __restrict__ bw, float* __restrict__ bpi) {
  int col = blockIdx.x; int c = threadIdx.x; int n = col >> 6;
  size_t i = (size_t)col * 256 + c;
  float m = motion_t[i], p = phase_t[i], me = memory_t[i], d = dn_t[i];
  float b0 = bw[n * 3 + 0], b1 = bw[n * 3 + 1], b2 = bw[n * 3 + 2];
  size_t base = (size_t)col * 1024;
  bpi[base + 256 + c] = b0 * m + b1 * p + b2 * me;
  bpi[base + 512 + c] = m - p;
  bpi[base + 768 + c] = me - d;
}

// ---------------- pass 2: out = x + delta * sgate ----------------
__global__ __launch_bounds__(256) void final_kernel(
    const float* __restrict__ x, const float* __restrict__ delta_t,
    const float* __restrict__ sgate_t, float* __restrict__ out) {
  int nc = blockIdx.x; int n = nc >> 8; int c = nc & 255;
  int t = threadIdx.x;
  __shared__ float dlt[64];
  __shared__ float4 sgs4[64];
  if (t < 64) dlt[t] = delta_t[((size_t)n * 64 + t) * 256 + c];
  ((float*)sgs4)[t] = sgate_t[((size_t)n * 256 + t) * 256 + c];
  __syncthreads();
  const float4* x4 = (const float4*)x + (size_t)nc * 4096;
  float4* o4 = (float4*)out + (size_t)nc * 4096;
  int w = t >> 6, l = t & 63;
  float4 sg = sgs4[l];
  for (int i = 0; i < 16; ++i) {
    int s = w * 16 + i;
    float d = dlt[s];
    float4 v = x4[(size_t)s * 64 + l];
    v.x += d * sg.x; v.y += d * sg.y; v.z += d * sg.z; v.w += d * sg.w;
    o4[(size_t)s * 64 + l] = v;
  }
}

} // namespace

extern "C" void kernel_launch(void* const* d_in, const int* in_sizes, int n_in,
                              void* d_out, int out_size, void* d_ws, size_t ws_size,
                              hipStream_t stream) {
  const float* x      = (const float*)d_in[0];
  const float* ln_g   = (const float*)d_in[1];
  const float* ln_b   = (const float*)d_in[2];
  const float* mb_w3  = (const float*)d_in[3];
  const float* mb_s3  = (const float*)d_in[4];
  const float* mb_b3  = (const float*)d_in[5];
  const float* mb_w5  = (const float*)d_in[6];
  const float* mb_s5  = (const float*)d_in[7];
  const float* mb_b5  = (const float*)d_in[8];
  const float* mb_w7  = (const float*)d_in[9];
  const float* mb_s7  = (const float*)d_in[10];
  const float* mb_b7  = (const float*)d_in[11];
  const float* mf_w   = (const float*)d_in[12];
  const float* mf_s   = (const float*)d_in[13];
  const float* mf_b   = (const float*)d_in[14];
  const float* pg_w1  = (const float*)d_in[15];
  const float* pg_s1  = (const float*)d_in[16];
  const float* pg_b1  = (const float*)d_in[17];
  const float* pg_w2  = (const float*)d_in[18];
  const float* pg_b2  = (const float*)d_in[19];
  const float* pp_w   = (const float*)d_in[20];
  const float* pp_s   = (const float*)d_in[21];
  const float* pp_b   = (const float*)d_in[22];
  const float* mg_w   = (const float*)d_in[23];
  const float* mg_b   = (const float*)d_in[24];
  const float* mo_w1  = (const float*)d_in[25];
  const float* mo_s1  = (const float*)d_in[26];
  const float* mo_b1  = (const float*)d_in[27];
  const float* mo_w2  = (const float*)d_in[28];
  const float* rt_w1  = (const float*)d_in[29];
  const float* rt_b1  = (const float*)d_in[30];
  const float* rt_w2  = (const float*)d_in[31];
  const float* rt_b2  = (const float*)d_in[32];
  const float* bp_w1  = (const float*)d_in[33];
  const float* bp_s1  = (const float*)d_in[34];
  const float* bp_b1  = (const float*)d_in[35];
  const float* bp_w2  = (const float*)d_in[36];
  const float* res_sc = (const float*)d_in[37];
  const float* fg_w   = (const float*)d_in[38];
  const float* fg_b   = (const float*)d_in[39];
  const float* sg_w   = (const float*)d_in[40];
  const float* sg_s   = (const float*)d_in[41];
  const float* sg_b   = (const float*)d_in[42];
  float* ws = (float*)d_ws;
  float* out = (float*)d_out;

  prep_weights_kernel<<<15360, 256, 0, stream>>>(mb_w3, mb_w5, mb_w7, mf_w, mg_w,
      mo_w1, mo_w2, pp_w, bp_w1, bp_w2, fg_w, sg_w, ws);
  reduce_x_kernel<<<2048, 256, 0, stream>>>(x, ws + O_DESC, ws + O_SPT);
  ln_kernel<<<512, 256, 0, stream>>>(ws + O_DESC, ln_g, ln_b, ws + O_DN);
  prep_mi_kernel<<<512, 256, 0, stream>>>(ws + O_DN, ws + O_MIC, ws + O_GIB, ws + O_MOI, ws + O_BPI);
  fft_kernel<<<264, 256, 0, stream>>>(ws + O_DN, ws + O_FE, ws + O_MFRE, ws + O_MFIM);
  peak_kernel<<<8, 64, 0, stream>>>(ws + O_FE, ws + O_MFRE, ws + O_MFIM, ws + O_PK);
  conv_mb_kernel<3><<<dim3(8, 8, 4), 256, 0, stream>>>(ws + O_MIC, ws + O_WT3, ws + O_MPRE);
  conv_mb_kernel<5><<<dim3(8, 8, 4), 256, 0, stream>>>(ws + O_MIC, ws + O_WT5, ws + O_MPRE + 524288);
  conv_mb_kernel<7><<<dim3(8, 8, 4), 256, 0, stream>>>(ws + O_MIC, ws + O_WT7, ws + O_MPRE + 1048576);
  combine_kernel<<<512, 256, 0, stream>>>(ws + O_MPRE, mb_s3, mb_b3, mb_s5, mb_b5, mb_s7, mb_b7, ws + O_MSUM);
  gemm_kernel<256, 0><<<dim3(4, 64), 256, 0, stream>>>(ws + O_ATMF, ws + O_MSUM, ws + O_MOT, mf_s, mf_b, nullptr, nullptr);
  gemm_kernel<512, 1><<<dim3(4, 64), 256, 0, stream>>>(ws + O_ATMG, ws + O_GIB, ws + O_GATE, nullptr, mg_b, nullptr, nullptr);
  scan_kernel<<<8, 256, 0, stream>>>(ws + O_DN, ws + O_GATE, ws + O_MOI);
  gemm_kernel<768, 0><<<dim3(4, 64), 256, 0, stream>>>(ws + O_ATMO1, ws + O_MOI, ws + O_HMO, mo_s1, mo_b1, nullptr, nullptr);
  gemm_kernel<256, 2><<<dim3(4, 64), 256, 0, stream>>>(ws + O_ATMO2, ws + O_HMO, ws + O_MEM, nullptr, nullptr, nullptr, nullptr);
  pgate_kernel<<<512, 256, 0, stream>>>(ws + O_DN, ws + O_PK, pg_w1, pg_s1, pg_b1, pg_w2, pg_b2, ws + O_PPIN);
  gemm_kernel<256, 0><<<dim3(4, 64), 256, 0, stream>>>(ws + O_ATPP, ws + O_PPIN, ws + O_PHASE, pp_s, pp_b, nullptr, nullptr);
  gemm_kernel<256, 1><<<dim3(4, 64), 256, 0, stream>>>(ws + O_ATFG, ws + O_DN, ws + O_FGATE, nullptr, fg_b, nullptr, nullptr);
  router_kernel<<<8, 256, 0, stream>>>(ws + O_DN, ws + O_MOT, ws + O_MEM, ws + O_PK,
      rt_w1, rt_b1, rt_w2, rt_b2, ws + O_BW);
  bp_prep_kernel<<<512, 256, 0, stream>>>(ws + O_MOT, ws + O_PHASE, ws + O_MEM, ws + O_DN, ws + O_BW, ws + O_BPI);
  gemm_kernel<1024, 0><<<dim3(4, 64), 256, 0, stream>>>(ws + O_ATBP1, ws + O_BPI, ws + O_HBP, bp_s1, bp_b1, nullptr, nullptr);
  gemm_kernel<256, 3><<<dim3(4, 64), 256, 0, stream>>>(ws + O_ATBP2, ws + O_HBP, ws + O_DELTA, nullptr, nullptr, ws + O_FGATE, res_sc);
  gemm_kernel<256, 4><<<dim3(4, 256), 256, 0, stream>>>(ws + O_ATSG, ws + O_SPT, ws + O_SGATE, sg_s, sg_b, nullptr, nullptr);
  final_kernel<<<2048, 256, 0, stream>>>(x, ws + O_DELTA, ws + O_SGATE, out);
}

// Round 2
// 699.426 us; speedup vs baseline: 1.2294x; 1.2294x over previous
//
#include <hip/hip_runtime.h>
#include <math.h>

namespace {

constexpr int N_ = 8, C_ = 256, S_ = 64, HW_ = 256;
constexpr int NS = N_ * S_;      // 512 columns (n,s)
constexpr int NHW = N_ * HW_;    // 2048 columns (n,hw)

// ---- workspace layout (float offsets) ----
constexpr size_t SZ_DESC = (size_t)NS * C_;           // 131072
constexpr size_t O_DESC = 0;
constexpr size_t O_DN   = O_DESC + SZ_DESC;
constexpr size_t SZ_MIC = (size_t)N_ * 768 * 80;      // padded rows of 80
constexpr size_t O_MIC  = O_DN + SZ_DESC;
constexpr size_t SZ_MPRE = (size_t)3 * 4 * 2048 * 64; // [conv][icpart][n*256+o][s]
constexpr size_t O_MPRE = O_MIC + SZ_MIC;
constexpr size_t O_MSUM = O_MPRE + SZ_MPRE;
constexpr size_t O_MOT  = O_MSUM + SZ_DESC;
constexpr size_t SZ_GIB = (size_t)NS * 512;
constexpr size_t O_GIB  = O_MOT + SZ_DESC;
constexpr size_t O_GATE = O_GIB + SZ_GIB;
constexpr size_t SZ_MOI = (size_t)NS * 768;
constexpr size_t O_MOI  = O_GATE + SZ_DESC;
constexpr size_t O_HMO  = O_MOI + SZ_MOI;
constexpr size_t O_MEM  = O_HMO + SZ_DESC;
constexpr size_t O_PPIN = O_MEM + SZ_DESC;
constexpr size_t O_PHASE= O_PPIN + SZ_DESC;
constexpr size_t O_FGATE= O_PHASE + SZ_DESC;
constexpr size_t SZ_BPI = (size_t)NS * 1024;
constexpr size_t O_BPI  = O_FGATE + SZ_DESC;
constexpr size_t O_HBP  = O_BPI + SZ_BPI;
constexpr size_t O_DELTA= O_HBP + SZ_DESC;
constexpr size_t SZ_SPT = (size_t)NHW * C_;
constexpr size_t O_SPT  = O_DELTA + SZ_DESC;
constexpr size_t O_SGATE= O_SPT + SZ_SPT;
constexpr size_t O_FE   = O_SGATE + SZ_SPT;   // 264 used, 512 reserved
constexpr size_t O_MFRE = O_FE + 512;
constexpr size_t O_MFIM = O_MFRE + 512;
constexpr size_t O_PK   = O_MFIM + 512;       // [n][4]: conf, pnorm, dphase, ang
constexpr size_t O_BW   = O_PK + 32;          // [n][3]
constexpr size_t SZ_WT3 = (size_t)768*3*256;
constexpr size_t O_WT3  = O_BW + 32;
constexpr size_t SZ_WT5 = (size_t)768*5*256;
constexpr size_t O_WT5  = O_WT3 + SZ_WT3;
constexpr size_t SZ_WT7 = (size_t)768*7*256;
constexpr size_t O_WT7  = O_WT5 + SZ_WT5;
constexpr size_t O_ATMF = O_WT7 + SZ_WT7;
constexpr size_t O_ATMG = O_ATMF + 256*256;
constexpr size_t O_ATMO1= O_ATMG + 512*256;
constexpr size_t O_ATMO2= O_ATMO1 + 768*256;
constexpr size_t O_ATPP = O_ATMO2 + 256*256;
constexpr size_t O_ATBP1= O_ATPP + 256*256;
constexpr size_t O_ATBP2= O_ATBP1 + 1024*256;
constexpr size_t O_ATFG = O_ATBP2 + 256*256;
constexpr size_t O_ATSG = O_ATFG + 256*256;

__device__ __forceinline__ float gelu_f(float v) {
  return 0.5f * v * (1.0f + erff(v * 0.70710678118654752f));
}
__device__ __forceinline__ float sigmoid_f(float v) {
  return 1.0f / (1.0f + expf(-v));
}

// block (256 threads) sum with broadcast; scratch = 4 floats in LDS
__device__ __forceinline__ float block_sum256(float v, float* scratch) {
  #pragma unroll
  for (int off = 32; off; off >>= 1) v += __shfl_down(v, off, 64);
  int w = threadIdx.x >> 6;
  __syncthreads();
  if ((threadIdx.x & 63) == 0) scratch[w] = v;
  __syncthreads();
  return scratch[0] + scratch[1] + scratch[2] + scratch[3];
}

// ---------------- weight repack: LDS-tiled transpose (coalesced both sides) ----------------
// All matrices are 256 rows (o) x K cols. Out: [k][o].
__global__ __launch_bounds__(256) void transpose_kernel(
    const float* __restrict__ w3, const float* __restrict__ w5, const float* __restrict__ w7,
    const float* __restrict__ wmf, const float* __restrict__ wmg,
    const float* __restrict__ wmo1, const float* __restrict__ wmo2,
    const float* __restrict__ wpp, const float* __restrict__ wbp1,
    const float* __restrict__ wbp2, const float* __restrict__ wfg,
    const float* __restrict__ wsg, float* __restrict__ ws) {
  __shared__ float tile[32][33];
  int xt = blockIdx.x, yt = blockIdx.y;
  const float* src; float* dst; int K;
  if      (xt < 72)  { src = w3;   dst = ws + O_WT3;   K = 2304; }
  else if (xt < 192) { src = w5;   dst = ws + O_WT5;   K = 3840; xt -= 72; }
  else if (xt < 360) { src = w7;   dst = ws + O_WT7;   K = 5376; xt -= 192; }
  else if (xt < 368) { src = wmf;  dst = ws + O_ATMF;  K = 256;  xt -= 360; }
  else if (xt < 384) { src = wmg;  dst = ws + O_ATMG;  K = 512;  xt -= 368; }
  else if (xt < 408) { src = wmo1; dst = ws + O_ATMO1; K = 768;  xt -= 384; }
  else if (xt < 416) { src = wmo2; dst = ws + O_ATMO2; K = 256;  xt -= 408; }
  else if (xt < 424) { src = wpp;  dst = ws + O_ATPP;  K = 256;  xt -= 416; }
  else if (xt < 456) { src = wbp1; dst = ws + O_ATBP1; K = 1024; xt -= 424; }
  else if (xt < 464) { src = wbp2; dst = ws + O_ATBP2; K = 256;  xt -= 456; }
  else if (xt < 472) { src = wfg;  dst = ws + O_ATFG;  K = 256;  xt -= 464; }
  else               { src = wsg;  dst = ws + O_ATSG;  K = 256;  xt -= 472; }
  int tx = threadIdx.x & 31, ty = threadIdx.x >> 5;
  int c = xt * 32 + tx;
  #pragma unroll
  for (int i = 0; i < 4; ++i) {
    int r = yt * 32 + ty + i * 8;
    tile[ty + i * 8][tx] = src[(size_t)r * K + c];
  }
  __syncthreads();
  #pragma unroll
  for (int i = 0; i < 4; ++i) {
    int cc = xt * 32 + ty + i * 8;
    dst[(size_t)cc * 256 + yt * 32 + tx] = tile[tx][ty + i * 8];
  }
}

// ---------------- pass 1: x reductions ----------------
__global__ __launch_bounds__(256) void reduce_x_kernel(
    const float* __restrict__ x, float* __restrict__ desc_t, float* __restrict__ sp_t) {
  int nc = blockIdx.x; int n = nc >> 8; int c = nc & 255;
  int t = threadIdx.x; int w = t >> 6; int l = t & 63;
  const float4* x4 = (const float4*)x + (size_t)nc * 4096;
  float4 sa = {0.f, 0.f, 0.f, 0.f};
  for (int i = 0; i < 16; ++i) {
    int s = w * 16 + i;
    float4 v = x4[(size_t)s * 64 + l];
    sa.x += v.x; sa.y += v.y; sa.z += v.z; sa.w += v.w;
    float ds = v.x + v.y + v.z + v.w;
    #pragma unroll
    for (int off = 32; off; off >>= 1) ds += __shfl_down(ds, off, 64);
    if (l == 0) desc_t[((size_t)n * 64 + s) * 256 + c] = ds * (1.f / 256.f);
  }
  __shared__ float4 lsp[4][64];
  lsp[w][l] = sa;
  __syncthreads();
  if (t < 64) {
    float4 a = lsp[0][t], b = lsp[1][t], c2 = lsp[2][t], d = lsp[3][t];
    float4 tot;
    tot.x = a.x + b.x + c2.x + d.x; tot.y = a.y + b.y + c2.y + d.y;
    tot.z = a.z + b.z + c2.z + d.z; tot.w = a.w + b.w + c2.w + d.w;
    size_t base = ((size_t)n * 256 + t * 4) * 256 + c;
    sp_t[base]       = tot.x * (1.f / 64.f);
    sp_t[base + 256] = tot.y * (1.f / 64.f);
    sp_t[base + 512] = tot.z * (1.f / 64.f);
    sp_t[base + 768] = tot.w * (1.f / 64.f);
  }
}

// ---------------- LayerNorm over C per (n,s) ----------------
__global__ __launch_bounds__(256) void ln_kernel(
    const float* __restrict__ desc_t, const float* __restrict__ g,
    const float* __restrict__ b, float* __restrict__ dn_t) {
  __shared__ float sc[4];
  int col = blockIdx.x; int t = threadIdx.x;
  float v = desc_t[(size_t)col * 256 + t];
  float s1 = block_sum256(v, sc);
  float s2 = block_sum256(v * v, sc);
  float mu = s1 * (1.f / 256.f);
  float var = s2 * (1.f / 256.f) - mu * mu;
  float r = rsqrtf(var + 1e-5f);
  dn_t[(size_t)col * 256 + t] = (v - mu) * r * g[t] + b[t];
}

// ---------------- diffs + staging buffers ----------------
__global__ __launch_bounds__(256) void prep_mi_kernel(
    const float* __restrict__ dn_t, float* __restrict__ mi_c,
    float* __restrict__ gib, float* __restrict__ moi, float* __restrict__ bpi) {
  int col = blockIdx.x; int c = threadIdx.x;
  int n = col >> 6, s = col & 63;
  float d = dn_t[(size_t)col * 256 + c];
  float d1 = (s >= 1) ? d - dn_t[(size_t)(col - 1) * 256 + c] : 0.f;
  float d2 = (s >= 2) ? d - dn_t[(size_t)(col - 2) * 256 + c] : 0.f;
  size_t r0 = ((size_t)n * 768 + c) * 80;
  size_t r1 = ((size_t)n * 768 + 256 + c) * 80;
  size_t r2 = ((size_t)n * 768 + 512 + c) * 80;
  mi_c[r0 + 8 + s] = d; mi_c[r1 + 8 + s] = d1; mi_c[r2 + 8 + s] = d2;
  if (s < 8)  { mi_c[r0 + s] = 0.f; mi_c[r1 + s] = 0.f; mi_c[r2 + s] = 0.f; }
  if (s >= 56){ int p = 72 + (s - 56); mi_c[r0 + p] = 0.f; mi_c[r1 + p] = 0.f; mi_c[r2 + p] = 0.f; }
  gib[(size_t)col * 512 + c] = d;
  gib[(size_t)col * 512 + 256 + c] = fabsf(d1);
  moi[(size_t)col * 768 + c] = d;
  bpi[(size_t)col * 1024 + c] = d;
}

// ---------------- rFFT over S (direct DFT) ----------------
__global__ __launch_bounds__(256) void fft_kernel(
    const float* __restrict__ dn_t, float* __restrict__ fe,
    float* __restrict__ mfre, float* __restrict__ mfim) {
  int b = blockIdx.x; int n = b / 33; int f = b % 33;
  int t = threadIdx.x;
  __shared__ float cs[64], sn[64];
  __shared__ float sc[4];
  if (t < 64) {
    int ft = (f * t) & 63;
    float ang = -6.283185307179586f * (float)ft * (1.f / 64.f);
    cs[t] = cosf(ang); sn[t] = sinf(ang);
  }
  __syncthreads();
  float re = 0.f, im = 0.f;
  const float* base = dn_t + (size_t)n * 16384 + t;
  for (int s = 0; s < 64; ++s) {
    float v = base[(size_t)s * 256];
    re += v * cs[s]; im += v * sn[s];
  }
  re *= 0.125f; im *= 0.125f;   // ortho 1/sqrt(64)
  float mag = sqrtf(re * re + im * im);
  float sm = block_sum256(mag, sc);
  float sr = block_sum256(re, sc);
  float si = block_sum256(im, sc);
  if (t == 0) {
    fe[b]   = sm * (1.f / 256.f);
    mfre[b] = sr * (1.f / 256.f);
    mfim[b] = si * (1.f / 256.f);
  }
}

// ---------------- peak / phase params per n ----------------
__global__ __launch_bounds__(64) void peak_kernel(
    const float* __restrict__ fe, const float* __restrict__ mfre,
    const float* __restrict__ mfim, float* __restrict__ pk) {
  int n = blockIdx.x; int t = threadIdx.x;
  float v = (t < 26) ? fe[n * 33 + 7 + t] : -1e30f;
  int idx = t;
  float hs = (t < 26) ? v : 0.f;
  #pragma unroll
  for (int off = 32; off; off >>= 1) {
    float ov = __shfl_down(v, off, 64);
    int   oi = __shfl_down(idx, off, 64);
    float oh = __shfl_down(hs, off, 64);
    hs += oh;
    if (ov > v || (ov == v && oi < idx)) { v = ov; idx = oi; }
  }
  if (t == 0) {
    int pi = idx + 7;
    float conf = v / fmaxf(hs, 1e-6f);
    float pnorm = (float)pi * (1.f / 32.f);
    float re = mfre[n * 33 + pi], im = mfim[n * 33 + pi];
    float dph = atan2f(im, re);
    float ang = (6.283185307179586f / 64.f) * (float)pi;
    pk[n * 4 + 0] = conf; pk[n * 4 + 1] = pnorm; pk[n * 4 + 2] = dph; pk[n * 4 + 3] = ang;
  }
}

// ---------------- fused motion convs (k = 3,5,7 in one pass), LDS-staged input ----------------
// grid (n=8, part=4, ot=8); block 256 = 32 o-lanes x 8 s-octs. 192 ic per part.
__global__ __launch_bounds__(256) void conv_fused_kernel(
    const float* __restrict__ mi_c, const float* __restrict__ wt3,
    const float* __restrict__ wt5, const float* __restrict__ wt7,
    float* __restrict__ mpre) {
  int n = blockIdx.x, part = blockIdx.y, ot = blockIdx.z;
  int t = threadIdx.x;
  __shared__ float lmi[192 * 80];   // 61440 B
  {
    const float4* src = (const float4*)(mi_c + ((size_t)n * 768 + part * 192) * 80);
    float4* dst = (float4*)lmi;
    #pragma unroll
    for (int i = 0; i < 15; ++i) dst[t + i * 256] = src[t + i * 256];
  }
  __syncthreads();
  int o = ot * 32 + (t & 31);
  int s0 = (t >> 5) * 8;
  float a3[8], a5[8], a7[8];
  #pragma unroll
  for (int j = 0; j < 8; ++j) { a3[j] = 0.f; a5[j] = 0.f; a7[j] = 0.f; }
  const float* w3p = wt3 + (size_t)(part * 192 * 3) * 256 + o;
  const float* w5p = wt5 + (size_t)(part * 192 * 5) * 256 + o;
  const float* w7p = wt7 + (size_t)(part * 192 * 7) * 256 + o;
  const float* lrow = lmi + 8 + s0 - 3;   // window base for k=7 (s-3)
  for (int ic = 0; ic < 192; ++ic) {
    float win[14];
    #pragma unroll
    for (int j = 0; j < 14; ++j) win[j] = lrow[ic * 80 + j];
    #pragma unroll
    for (int dk = 0; dk < 7; ++dk) {
      float w = w7p[(size_t)(ic * 7 + dk) * 256];
      #pragma unroll
      for (int j = 0; j < 8; ++j) a7[j] = fmaf(w, win[dk + j], a7[j]);
    }
    #pragma unroll
    for (int dk = 0; dk < 5; ++dk) {
      float w = w5p[(size_t)(ic * 5 + dk) * 256];
      #pragma unroll
      for (int j = 0; j < 8; ++j) a5[j] = fmaf(w, win[1 + dk + j], a5[j]);
    }
    #pragma unroll
    for (int dk = 0; dk < 3; ++dk) {
      float w = w3p[(size_t)(ic * 3 + dk) * 256];
      #pragma unroll
      for (int j = 0; j < 8; ++j) a3[j] = fmaf(w, win[2 + dk + j], a3[j]);
    }
  }
  size_t base = ((size_t)part * 2048 + n * 256 + o) * 64 + s0;
  #pragma unroll
  for (int j = 0; j < 8; ++j) {
    mpre[base + j]           = a3[j];
    mpre[base + 524288 + j]  = a5[j];
    mpre[base + 1048576 + j] = a7[j];
  }
}

// ---------------- combine partials: gelu(bn) sum over 3 convs, /3 ----------------
__global__ __launch_bounds__(256) void combine_kernel(
    const float* __restrict__ mpre,
    const float* __restrict__ s3, const float* __restrict__ b3,
    const float* __restrict__ s5, const float* __restrict__ b5,
    const float* __restrict__ s7, const float* __restrict__ b7,
    float* __restrict__ msum) {
  int id = blockIdx.x * 256 + threadIdx.x;
  int s = id & 63; int o = (id >> 6) & 255; int n = id >> 14;
  size_t base = ((size_t)n * 256 + o) * 64 + s;
  float v0 = mpre[base] + mpre[base + 131072] + mpre[base + 262144] + mpre[base + 393216];
  size_t b5o = base + 524288;
  float v1 = mpre[b5o] + mpre[b5o + 131072] + mpre[b5o + 262144] + mpre[b5o + 393216];
  size_t b7o = base + 1048576;
  float v2 = mpre[b7o] + mpre[b7o + 131072] + mpre[b7o + 262144] + mpre[b7o + 393216];
  float tot = gelu_f(v0 * s3[o] + b3[o]) + gelu_f(v1 * s5[o] + b5[o]) + gelu_f(v2 * s7[o] + b7[o]);
  msum[((size_t)n * 64 + s) * 256 + o] = tot * (1.f / 3.f);
}

// ---------------- generic 1x1-conv GEMM ----------------
// EPI: 0 = gelu(v*sc+bi); 1 = sigmoid(v+bi); 2 = none; 3 = v*fg[col][o]*rs[o]; 4 = sigmoid(v*sc+bi)
template <int K, int EPI>
__global__ __launch_bounds__(256) void gemm_kernel(
    const float* __restrict__ At, const float* __restrict__ B, float* __restrict__ out,
    const float* __restrict__ sc, const float* __restrict__ bi,
    const float* __restrict__ fg, const float* __restrict__ rs) {
  int t = threadIdx.x;
  int o = blockIdx.x * 64 + (t & 63);
  int c0 = blockIdx.y * 8 + (t >> 6) * 2;
  const float* b0p = B + (size_t)c0 * K;
  const float* b1p = b0p + K;
  float4 a0 = {0.f,0.f,0.f,0.f}, a1 = {0.f,0.f,0.f,0.f};
  for (int kk = 0; kk < K; kk += 4) {
    float4 b0 = *(const float4*)(b0p + kk);
    float4 b1 = *(const float4*)(b1p + kk);
    float w0 = At[(size_t)(kk + 0) * 256 + o];
    float w1 = At[(size_t)(kk + 1) * 256 + o];
    float w2 = At[(size_t)(kk + 2) * 256 + o];
    float w3 = At[(size_t)(kk + 3) * 256 + o];
    a0.x += w0 * b0.x; a0.y += w1 * b0.y; a0.z += w2 * b0.z; a0.w += w3 * b0.w;
    a1.x += w0 * b1.x; a1.y += w1 * b1.y; a1.z += w2 * b1.z; a1.w += w3 * b1.w;
  }
  float v0 = (a0.x + a0.y) + (a0.z + a0.w);
  float v1 = (a1.x + a1.y) + (a1.z + a1.w);
  if constexpr (EPI == 0) { v0 = gelu_f(v0 * sc[o] + bi[o]); v1 = gelu_f(v1 * sc[o] + bi[o]); }
  else if constexpr (EPI == 1) { v0 = sigmoid_f(v0 + bi[o]); v1 = sigmoid_f(v1 + bi[o]); }
  else if constexpr (EPI == 3) {
    v0 *= fg[(size_t)c0 * 256 + o] * rs[o];
    v1 *= fg[(size_t)(c0 + 1) * 256 + o] * rs[o];
  }
  else if constexpr (EPI == 4) { v0 = sigmoid_f(v0 * sc[o] + bi[o]); v1 = sigmoid_f(v1 * sc[o] + bi[o]); }
  out[(size_t)c0 * 256 + o] = v0;
  out[(size_t)(c0 + 1) * 256 + o] = v1;
}

// ---------------- gated fwd/bwd scan over S (LDS-staged) ----------------
// grid (n=8, half=2); block 256: t<128 fwd, t>=128 bwd; each handles 128 channels.
__global__ __launch_bounds__(256) void scan_kernel(
    const float* __restrict__ dn_t, const float* __restrict__ gate_t, float* __restrict__ moi) {
  int n = blockIdx.x, half = blockIdx.y;
  int t = threadIdx.x;
  __shared__ float ld[64 * 128];
  __shared__ float lg[64 * 128];
  const float* dsrc = dn_t + (size_t)n * 16384 + half * 128;
  const float* gsrc = gate_t + (size_t)n * 16384 + half * 128;
  for (int i = t; i < 8192; i += 256) {
    int s = i >> 7, j = i & 127;
    ld[i] = dsrc[(size_t)s * 256 + j];
    lg[i] = gsrc[(size_t)s * 256 + j];
  }
  __syncthreads();
  int cl = t & 127;
  int c = half * 128 + cl;
  size_t ob = (size_t)n * 64 * 768 + c;
  if (t < 128) {
    float st = ld[cl];
    moi[ob + 256] = st;
    for (int s = 1; s < 64; ++s) {
      float g = lg[s * 128 + cl], d = ld[s * 128 + cl];
      st = g * st + (1.f - g) * d;
      moi[ob + (size_t)s * 768 + 256] = st;
    }
  } else {
    float st = ld[63 * 128 + cl];
    moi[ob + (size_t)63 * 768 + 512] = st;
    for (int s = 62; s >= 0; --s) {
      float g = lg[s * 128 + cl], d = ld[s * 128 + cl];
      st = g * st + (1.f - g) * d;
      moi[ob + (size_t)s * 768 + 512] = st;
    }
  }
}

// ---------------- phase gate ----------------
__global__ __launch_bounds__(256) void pgate_kernel(
    const float* __restrict__ dn_t, const float* __restrict__ pk,
    const float* __restrict__ pg_w1, const float* __restrict__ pg_s1, const float* __restrict__ pg_b1,
    const float* __restrict__ pg_w2, const float* __restrict__ pg_b2, float* __restrict__ ppin) {
  int col = blockIdx.x; int n = col >> 6; int s = col & 63;
  int t = threadIdx.x;
  __shared__ float h[64];
  float conf = pk[n * 4 + 0], dph = pk[n * 4 + 2], ang = pk[n * 4 + 3];
  float arg = ang * (float)s + dph;
  float pc = cosf(arg), ps = sinf(arg);
  if (t < 64) {
    float v = pg_w1[t * 3 + 0] * pc + pg_w1[t * 3 + 1] * ps + pg_w1[t * 3 + 2] * conf;
    v = v * pg_s1[t] + pg_b1[t];
    h[t] = gelu_f(v);
  }
  __syncthreads();
  float acc = pg_b2[t];
  const float* wrow = pg_w2 + t * 64;
  #pragma unroll 8
  for (int j = 0; j < 64; ++j) acc += wrow[j] * h[j];
  float pg = sigmoid_f(acc);
  ppin[(size_t)col * 256 + t] = dn_t[(size_t)col * 256 + t] * pg;
}

// ---------------- router ----------------
__global__ __launch_bounds__(256) void router_kernel(
    const float* __restrict__ dn_t, const float* __restrict__ motion_t,
    const float* __restrict__ memory_t, const float* __restrict__ pk,
    const float* __restrict__ rt_w1, const float* __restrict__ rt_b1,
    const float* __restrict__ rt_w2, const float* __restrict__ rt_b2,
    float* __restrict__ bw) {
  int n = blockIdx.x; int c = threadIdx.x;
  __shared__ float ri[261];
  __shared__ float h2[64];
  __shared__ float lg[3];
  __shared__ float sc[4];
  float sum = 0.f, sq = 0.f, ad1 = 0.f, amot = 0.f, amem = 0.f, prev = 0.f;
  for (int s = 0; s < 64; ++s) {
    size_t i = ((size_t)n * 64 + s) * 256 + c;
    float d = dn_t[i];
    sum += d; sq += d * d;
    if (s > 0) ad1 += fabsf(d - prev);
    prev = d;
    amot += fabsf(motion_t[i]);
    amem += fabsf(memory_t[i] - d);
  }
  float mean = sum * (1.f / 64.f);
  float var = sq * (1.f / 64.f) - mean * mean;
  float stdc = sqrtf(fmaxf(var, 0.f));
  ri[c] = mean;
  float rstd = block_sum256(stdc, sc);
  float rad1 = block_sum256(ad1, sc);
  float rmot = block_sum256(amot, sc);
  float rmem = block_sum256(amem, sc);
  if (c == 0) {
    ri[256] = rstd * (1.f / 256.f);
    ri[257] = rad1 * (1.f / 16384.f);
    ri[258] = pk[n * 4 + 0];
    ri[259] = pk[n * 4 + 1];
    ri[260] = (rmem + rmot) * (1.f / 16384.f);
  }
  __syncthreads();
  if (c < 64) {
    float acc = rt_b1[c];
    const float* wrow = rt_w1 + c * 261;
    for (int i = 0; i < 261; ++i) acc += wrow[i] * ri[i];
    h2[c] = gelu_f(acc);
  }
  __syncthreads();
  if (c < 3) {
    float acc = rt_b2[c];
    const float* wrow = rt_w2 + c * 64;
    #pragma unroll 8
    for (int j = 0; j < 64; ++j) acc += wrow[j] * h2[j];
    lg[c] = acc;
  }
  __syncthreads();
  if (c == 0) {
    float m = fmaxf(lg[0], fmaxf(lg[1], lg[2]));
    float e0 = expf(lg[0] - m), e1 = expf(lg[1] - m), e2 = expf(lg[2] - m);
    float inv = 1.f / (e0 + e1 + e2);
    bw[n * 3 + 0] = e0 * inv; bw[n * 3 + 1] = e1 * inv; bw[n * 3 + 2] = e2 * inv;
  }
}

// ---------------- build bp input rows 256..1023 ----------------
__global__ __launch_bounds__(256) void bp_prep_kernel(
    const float* __restrict__ motion_t, const float* __restrict__ phase_t,
    const float* __restrict__ memory_t, const float* __restrict__ dn_t,
    const float* __restrict__ bw, float* __restrict__ bpi) {
  int col = blockIdx.x; int c = threadIdx.x; int n = col >> 6;
  size_t i = (size_t)col * 256 + c;
  float m = motion_t[i], p = phase_t[i], me = memory_t[i], d = dn_t[i];
  float b0 = bw[n * 3 + 0], b1 = bw[n * 3 + 1], b2 = bw[n * 3 + 2];
  size_t base = (size_t)col * 1024;
  bpi[base + 256 + c] = b0 * m + b1 * p + b2 * me;
  bpi[base + 512 + c] = m - p;
  bpi[base + 768 + c] = me - d;
}

// ---------------- pass 2: out = x + delta * sgate ----------------
__global__ __launch_bounds__(256) void final_kernel(
    const float* __restrict__ x, const float* __restrict__ delta_t,
    const float* __restrict__ sgate_t, float* __restrict__ out) {
  int nc = blockIdx.x; int n = nc >> 8; int c = nc & 255;
  int t = threadIdx.x;
  __shared__ float dlt[64];
  __shared__ float4 sgs4[64];
  if (t < 64) dlt[t] = delta_t[((size_t)n * 64 + t) * 256 + c];
  ((float*)sgs4)[t] = sgate_t[((size_t)n * 256 + t) * 256 + c];
  __syncthreads();
  const float4* x4 = (const float4*)x + (size_t)nc * 4096;
  float4* o4 = (float4*)out + (size_t)nc * 4096;
  int w = t >> 6, l = t & 63;
  float4 sg = sgs4[l];
  for (int i = 0; i < 16; ++i) {
    int s = w * 16 + i;
    float d = dlt[s];
    float4 v = x4[(size_t)s * 64 + l];
    v.x += d * sg.x; v.y += d * sg.y; v.z += d * sg.z; v.w += d * sg.w;
    o4[(size_t)s * 64 + l] = v;
  }
}

} // namespace

extern "C" void kernel_launch(void* const* d_in, const int* in_sizes, int n_in,
                              void* d_out, int out_size, void* d_ws, size_t ws_size,
                              hipStream_t stream) {
  const float* x      = (const float*)d_in[0];
  const float* ln_g   = (const float*)d_in[1];
  const float* ln_b   = (const float*)d_in[2];
  const float* mb_w3  = (const float*)d_in[3];
  const float* mb_s3  = (const float*)d_in[4];
  const float* mb_b3  = (const float*)d_in[5];
  const float* mb_w5  = (const float*)d_in[6];
  const float* mb_s5  = (const float*)d_in[7];
  const float* mb_b5  = (const float*)d_in[8];
  const float* mb_w7  = (const float*)d_in[9];
  const float* mb_s7  = (const float*)d_in[10];
  const float* mb_b7  = (const float*)d_in[11];
  const float* mf_w   = (const float*)d_in[12];
  const float* mf_s   = (const float*)d_in[13];
  const float* mf_b   = (const float*)d_in[14];
  const float* pg_w1  = (const float*)d_in[15];
  const float* pg_s1  = (const float*)d_in[16];
  const float* pg_b1  = (const float*)d_in[17];
  const float* pg_w2  = (const float*)d_in[18];
  const float* pg_b2  = (const float*)d_in[19];
  const float* pp_w   = (const float*)d_in[20];
  const float* pp_s   = (const float*)d_in[21];
  const float* pp_b   = (const float*)d_in[22];
  const float* mg_w   = (const float*)d_in[23];
  const float* mg_b   = (const float*)d_in[24];
  const float* mo_w1  = (const float*)d_in[25];
  const float* mo_s1  = (const float*)d_in[26];
  const float* mo_b1  = (const float*)d_in[27];
  const float* mo_w2  = (const float*)d_in[28];
  const float* rt_w1  = (const float*)d_in[29];
  const float* rt_b1  = (const float*)d_in[30];
  const float* rt_w2  = (const float*)d_in[31];
  const float* rt_b2  = (const float*)d_in[32];
  const float* bp_w1  = (const float*)d_in[33];
  const float* bp_s1  = (const float*)d_in[34];
  const float* bp_b1  = (const float*)d_in[35];
  const float* bp_w2  = (const float*)d_in[36];
  const float* res_sc = (const float*)d_in[37];
  const float* fg_w   = (const float*)d_in[38];
  const float* fg_b   = (const float*)d_in[39];
  const float* sg_w   = (const float*)d_in[40];
  const float* sg_s   = (const float*)d_in[41];
  const float* sg_b   = (const float*)d_in[42];
  float* ws = (float*)d_ws;
  float* out = (float*)d_out;

  transpose_kernel<<<dim3(480, 8), 256, 0, stream>>>(mb_w3, mb_w5, mb_w7, mf_w, mg_w,
      mo_w1, mo_w2, pp_w, bp_w1, bp_w2, fg_w, sg_w, ws);
  reduce_x_kernel<<<2048, 256, 0, stream>>>(x, ws + O_DESC, ws + O_SPT);
  ln_kernel<<<512, 256, 0, stream>>>(ws + O_DESC, ln_g, ln_b, ws + O_DN);
  prep_mi_kernel<<<512, 256, 0, stream>>>(ws + O_DN, ws + O_MIC, ws + O_GIB, ws + O_MOI, ws + O_BPI);
  fft_kernel<<<264, 256, 0, stream>>>(ws + O_DN, ws + O_FE, ws + O_MFRE, ws + O_MFIM);
  peak_kernel<<<8, 64, 0, stream>>>(ws + O_FE, ws + O_MFRE, ws + O_MFIM, ws + O_PK);
  conv_fused_kernel<<<dim3(8, 4, 8), 256, 0, stream>>>(ws + O_MIC, ws + O_WT3, ws + O_WT5, ws + O_WT7, ws + O_MPRE);
  combine_kernel<<<512, 256, 0, stream>>>(ws + O_MPRE, mb_s3, mb_b3, mb_s5, mb_b5, mb_s7, mb_b7, ws + O_MSUM);
  gemm_kernel<256, 0><<<dim3(4, 64), 256, 0, stream>>>(ws + O_ATMF, ws + O_MSUM, ws + O_MOT, mf_s, mf_b, nullptr, nullptr);
  gemm_kernel<512, 1><<<dim3(4, 64), 256, 0, stream>>>(ws + O_ATMG, ws + O_GIB, ws + O_GATE, nullptr, mg_b, nullptr, nullptr);
  scan_kernel<<<dim3(8, 2), 256, 0, stream>>>(ws + O_DN, ws + O_GATE, ws + O_MOI);
  gemm_kernel<768, 0><<<dim3(4, 64), 256, 0, stream>>>(ws + O_ATMO1, ws + O_MOI, ws + O_HMO, mo_s1, mo_b1, nullptr, nullptr);
  gemm_kernel<256, 2><<<dim3(4, 64), 256, 0, stream>>>(ws + O_ATMO2, ws + O_HMO, ws + O_MEM, nullptr, nullptr, nullptr, nullptr);
  pgate_kernel<<<512, 256, 0, stream>>>(ws + O_DN, ws + O_PK, pg_w1, pg_s1, pg_b1, pg_w2, pg_b2, ws + O_PPIN);
  gemm_kernel<256, 0><<<dim3(4, 64), 256, 0, stream>>>(ws + O_ATPP, ws + O_PPIN, ws + O_PHASE, pp_s, pp_b, nullptr, nullptr);
  gemm_kernel<256, 1><<<dim3(4, 64), 256, 0, stream>>>(ws + O_ATFG, ws + O_DN, ws + O_FGATE, nullptr, fg_b, nullptr, nullptr);
  router_kernel<<<8, 256, 0, stream>>>(ws + O_DN, ws + O_MOT, ws + O_MEM, ws + O_PK,
      rt_w1, rt_b1, rt_w2, rt_b2, ws + O_BW);
  bp_prep_kernel<<<512, 256, 0, stream>>>(ws + O_MOT, ws + O_PHASE, ws + O_MEM, ws + O_DN, ws + O_BW, ws + O_BPI);
  gemm_kernel<1024, 0><<<dim3(4, 64), 256, 0, stream>>>(ws + O_ATBP1, ws + O_BPI, ws + O_HBP, bp_s1, bp_b1, nullptr, nullptr);
  gemm_kernel<256, 3><<<dim3(4, 64), 256, 0, stream>>>(ws + O_ATBP2, ws + O_HBP, ws + O_DELTA, nullptr, nullptr, ws + O_FGATE, res_sc);
  gemm_kernel<256, 4><<<dim3(4, 256), 256, 0, stream>>>(ws + O_ATSG, ws + O_SPT, ws + O_SGATE, sg_s, sg_b, nullptr, nullptr);
  final_kernel<<<2048, 256, 0, stream>>>(x, ws + O_DELTA, ws + O_SGATE, out);
}

// Round 3
// 604.778 us; speedup vs baseline: 1.4218x; 1.1565x over previous
//
#include <hip/hip_runtime.h>
#include <math.h>

namespace {

constexpr int N_ = 8, C_ = 256, S_ = 64, HW_ = 256;
constexpr int NS = N_ * S_;      // 512 columns (n,s)
constexpr int NHW = N_ * HW_;    // 2048 columns (n,hw)

// ---- workspace layout (float offsets) ----
constexpr size_t O_DESC  = 0;            // [512][256]
constexpr size_t O_DN    = 131072;
constexpr size_t O_MSUM  = 262144;
constexpr size_t O_MOT   = 393216;
constexpr size_t O_GATE  = 524288;
constexpr size_t O_HMO   = 655360;
constexpr size_t O_MEM   = 786432;
constexpr size_t O_PPIN  = 917504;
constexpr size_t O_PHASE = 1048576;
constexpr size_t O_FGATE = 1179648;
constexpr size_t O_HBP   = 1310720;
constexpr size_t O_DELTA = 1441792;
constexpr size_t O_GIB   = 1572864;      // [512][512]
constexpr size_t O_MOI   = 1835008;      // [512][768]
constexpr size_t O_BPI   = 2228224;      // [512][1024]
constexpr size_t O_SPT   = 2752512;      // [2048][256]
constexpr size_t O_SGATE = 3276800;      // [2048][256]
constexpr size_t O_FE    = 3801088;      // 264 used
constexpr size_t O_MFRE  = 3801600;
constexpr size_t O_MFIM  = 3802112;
constexpr size_t O_PK    = 3802624;      // [n][4]
constexpr size_t O_BW    = 3802656;      // [n][3]
constexpr size_t O_ATMF  = 3802688;
constexpr size_t O_ATMG  = 3868224;
constexpr size_t O_ATMO1 = 3999296;
constexpr size_t O_ATMO2 = 4195904;
constexpr size_t O_ATPP  = 4261440;
constexpr size_t O_ATBP1 = 4326976;
constexpr size_t O_ATBP2 = 4589120;
constexpr size_t O_ATFG  = 4654656;
constexpr size_t O_ATSG  = 4720192;
constexpr size_t O_WFRAG = 4785728;      // bf16 [168 kchunk][48 m16][64 lane][8] = 4,128,768 ushort
constexpr size_t O_IM2   = 6850112;      // bf16 [168 kchunk][32 c16][64 lane][8] = 2,752,512 ushort
constexpr size_t O_CONVC = 8226368;      // fp32 [4 kp][768][512]

typedef __attribute__((ext_vector_type(4))) float f32x4;
typedef __attribute__((ext_vector_type(8))) short s16x8;
typedef __attribute__((ext_vector_type(8))) unsigned short u16x8;

__device__ __forceinline__ float gelu_f(float v) {
  return 0.5f * v * (1.0f + erff(v * 0.70710678118654752f));
}
__device__ __forceinline__ float sigmoid_f(float v) {
  return 1.0f / (1.0f + expf(-v));
}
__device__ __forceinline__ unsigned short f2bf(float f) {
  unsigned int u = __float_as_uint(f);
  u += 0x7fffu + ((u >> 16) & 1u);
  return (unsigned short)(u >> 16);
}

// block (256 threads) sum with broadcast; scratch = 4 floats in LDS
__device__ __forceinline__ float block_sum256(float v, float* scratch) {
  #pragma unroll
  for (int off = 32; off; off >>= 1) v += __shfl_down(v, off, 64);
  int w = threadIdx.x >> 6;
  __syncthreads();
  if ((threadIdx.x & 63) == 0) scratch[w] = v;
  __syncthreads();
  return scratch[0] + scratch[1] + scratch[2] + scratch[3];
}

// ---------------- 1x1 weight repack: LDS-tiled transpose ----------------
__global__ __launch_bounds__(256) void transpose_kernel(
    const float* __restrict__ wmf, const float* __restrict__ wmg,
    const float* __restrict__ wmo1, const float* __restrict__ wmo2,
    const float* __restrict__ wpp, const float* __restrict__ wbp1,
    const float* __restrict__ wbp2, const float* __restrict__ wfg,
    const float* __restrict__ wsg, float* __restrict__ ws) {
  __shared__ float tile[32][33];
  int xt = blockIdx.x, yt = blockIdx.y;
  const float* src; float* dst; int K;
  if      (xt < 8)   { src = wmf;  dst = ws + O_ATMF;  K = 256;  }
  else if (xt < 24)  { src = wmg;  dst = ws + O_ATMG;  K = 512;  xt -= 8;  }
  else if (xt < 48)  { src = wmo1; dst = ws + O_ATMO1; K = 768;  xt -= 24; }
  else if (xt < 56)  { src = wmo2; dst = ws + O_ATMO2; K = 256;  xt -= 48; }
  else if (xt < 64)  { src = wpp;  dst = ws + O_ATPP;  K = 256;  xt -= 56; }
  else if (xt < 96)  { src = wbp1; dst = ws + O_ATBP1; K = 1024; xt -= 64; }
  else if (xt < 104) { src = wbp2; dst = ws + O_ATBP2; K = 256;  xt -= 96; }
  else if (xt < 112) { src = wfg;  dst = ws + O_ATFG;  K = 256;  xt -= 104;}
  else               { src = wsg;  dst = ws + O_ATSG;  K = 256;  xt -= 112;}
  int tx = threadIdx.x & 31, ty = threadIdx.x >> 5;
  int c = xt * 32 + tx;
  #pragma unroll
  for (int i = 0; i < 4; ++i) {
    int r = yt * 32 + ty + i * 8;
    tile[ty + i * 8][tx] = src[(size_t)r * K + c];
  }
  __syncthreads();
  #pragma unroll
  for (int i = 0; i < 4; ++i) {
    int cc = xt * 32 + ty + i * 8;
    dst[(size_t)cc * 256 + yt * 32 + tx] = tile[tx][ty + i * 8];
  }
}

// ---------------- conv weight pack into MFMA A-fragment order (bf16) ----------------
// W'[k=(ic*7+tau+3)][o'=conv*256+oc]; frag idx = (kchunk*48+m16)*64+lane, 8 bf16/lane
__global__ __launch_bounds__(256) void wfrag_kernel(
    const float* __restrict__ w3, const float* __restrict__ w5, const float* __restrict__ w7,
    unsigned short* __restrict__ wf) {
  int g = blockIdx.x * 256 + threadIdx.x;        // one lane-slot
  int lane = g & 63;
  int m16 = (g >> 6) % 48;
  int kchunk = (g >> 6) / 48;
  int o = m16 * 16 + (lane & 15);
  int conv = o >> 8, oc = o & 255;
  int q = lane >> 4;
  u16x8 out;
  #pragma unroll
  for (int j = 0; j < 8; ++j) {
    int k = kchunk * 32 + q * 8 + j;
    int ic = k / 7;
    int tau = k - ic * 7 - 3;
    float v = 0.f;
    if (conv == 0) {
      if (tau >= -1 && tau <= 1) v = w3[((size_t)oc * 768 + ic) * 3 + (tau + 1)];
    } else if (conv == 1) {
      if (tau >= -2 && tau <= 2) v = w5[((size_t)oc * 768 + ic) * 5 + (tau + 2)];
    } else {
      v = w7[((size_t)oc * 768 + ic) * 7 + (tau + 3)];
    }
    out[j] = f2bf(v);
  }
  *((u16x8*)wf + g) = out;
}

// ---------------- im2col into MFMA B-fragment order (bf16) ----------------
// A[k][col] = stream(ic>>8) value at (n, ic&255, s+tau); frag idx = (kchunk*32+c16)*64+lane
__global__ __launch_bounds__(256) void im2col_kernel(
    const float* __restrict__ dn_t, unsigned short* __restrict__ imf) {
  int g = blockIdx.x * 256 + threadIdx.x;
  int lane = g & 63;
  int c16 = (g >> 6) % 32;
  int kchunk = (g >> 6) / 32;
  int col = c16 * 16 + (lane & 15);
  int n = col >> 6, s = col & 63;
  int q = lane >> 4;
  const float* base = dn_t + (size_t)n * 16384;
  u16x8 out;
  #pragma unroll
  for (int j = 0; j < 8; ++j) {
    int k = kchunk * 32 + q * 8 + j;
    int ic = k / 7;
    int tau = k - ic * 7 - 3;
    int stream = ic >> 8, c = ic & 255;
    int sp = s + tau;
    float v = 0.f;
    if (sp >= 0 && sp < 64) {
      float d = base[(size_t)sp * 256 + c];
      if (stream == 0) v = d;
      else if (stream == 1) v = (sp >= 1) ? d - base[(size_t)(sp - 1) * 256 + c] : 0.f;
      else v = (sp >= 2) ? d - base[(size_t)(sp - 2) * 256 + c] : 0.f;
    }
    out[j] = f2bf(v);
  }
  *((u16x8*)imf + g) = out;
}

// ---------------- conv as MFMA GEMM: C[o'][col] = sum_k W'[k][o'] A[k][col] ----------------
// grid (mt=12, nt=8, kp=4); block 256 = 4 waves; wave w -> m16 = mt*4+w (16 o-rows x 64 cols)
__global__ __launch_bounds__(256) void conv_mfma_kernel(
    const unsigned short* __restrict__ wf, const unsigned short* __restrict__ imf,
    float* __restrict__ partial) {
  int mt = blockIdx.x, nt = blockIdx.y, kp = blockIdx.z;
  int lane = threadIdx.x & 63;
  int w = threadIdx.x >> 6;
  int m16 = mt * 4 + w;
  const s16x8* wfp = (const s16x8*)wf;
  const s16x8* imp = (const s16x8*)imf;
  f32x4 acc0 = {0.f,0.f,0.f,0.f}, acc1 = {0.f,0.f,0.f,0.f};
  f32x4 acc2 = {0.f,0.f,0.f,0.f}, acc3 = {0.f,0.f,0.f,0.f};
  #pragma unroll 2
  for (int cc = 0; cc < 42; ++cc) {
    int kc = kp * 42 + cc;
    s16x8 a = wfp[(size_t)(kc * 48 + m16) * 64 + lane];
    s16x8 b0 = imp[(size_t)(kc * 32 + nt * 4 + 0) * 64 + lane];
    s16x8 b1 = imp[(size_t)(kc * 32 + nt * 4 + 1) * 64 + lane];
    s16x8 b2 = imp[(size_t)(kc * 32 + nt * 4 + 2) * 64 + lane];
    s16x8 b3 = imp[(size_t)(kc * 32 + nt * 4 + 3) * 64 + lane];
    acc0 = __builtin_amdgcn_mfma_f32_16x16x32_bf16(a, b0, acc0, 0, 0, 0);
    acc1 = __builtin_amdgcn_mfma_f32_16x16x32_bf16(a, b1, acc1, 0, 0, 0);
    acc2 = __builtin_amdgcn_mfma_f32_16x16x32_bf16(a, b2, acc2, 0, 0, 0);
    acc3 = __builtin_amdgcn_mfma_f32_16x16x32_bf16(a, b3, acc3, 0, 0, 0);
  }
  int q = lane >> 4, ln = lane & 15;
  int o0 = m16 * 16 + q * 4;
  float* pb = partial + (size_t)kp * 393216;
  #pragma unroll
  for (int r = 0; r < 4; ++r) {
    size_t row = (size_t)(o0 + r) * 512;
    pb[row + (nt * 4 + 0) * 16 + ln] = acc0[r];
    pb[row + (nt * 4 + 1) * 16 + ln] = acc1[r];
    pb[row + (nt * 4 + 2) * 16 + ln] = acc2[r];
    pb[row + (nt * 4 + 3) * 16 + ln] = acc3[r];
  }
}

// ---------------- combine: sum kp, bn+gelu per conv, avg, transpose to [col][o] ----------------
__global__ __launch_bounds__(256) void combine_kernel(
    const float* __restrict__ P,
    const float* __restrict__ s3, const float* __restrict__ b3,
    const float* __restrict__ s5, const float* __restrict__ b5,
    const float* __restrict__ s7, const float* __restrict__ b7,
    float* __restrict__ msum) {
  __shared__ float tile[32][33];
  int col0 = blockIdx.x * 32, o0 = blockIdx.y * 32;
  int t = threadIdx.x;
  int cl = t & 31, orow = t >> 5;
  #pragma unroll
  for (int p = 0; p < 4; ++p) {
    int ol = p * 8 + orow;
    int o = o0 + ol, col = col0 + cl;
    float v3 = 0.f, v5 = 0.f, v7 = 0.f;
    #pragma unroll
    for (int kpp = 0; kpp < 4; ++kpp) {
      size_t base = (size_t)kpp * 393216 + col;
      v3 += P[base + (size_t)o * 512];
      v5 += P[base + (size_t)(o + 256) * 512];
      v7 += P[base + (size_t)(o + 512) * 512];
    }
    float tot = gelu_f(v3 * s3[o] + b3[o]) + gelu_f(v5 * s5[o] + b5[o]) + gelu_f(v7 * s7[o] + b7[o]);
    tile[ol][cl] = tot * (1.f / 3.f);
  }
  __syncthreads();
  #pragma unroll
  for (int p = 0; p < 4; ++p) {
    int coll = p * 8 + orow;
    msum[(size_t)(col0 + coll) * 256 + o0 + cl] = tile[cl][coll];
  }
}

// ---------------- pass 1: x reductions ----------------
__global__ __launch_bounds__(256) void reduce_x_kernel(
    const float* __restrict__ x, float* __restrict__ desc_t, float* __restrict__ sp_t) {
  int nc = blockIdx.x; int n = nc >> 8; int c = nc & 255;
  int t = threadIdx.x; int w = t >> 6; int l = t & 63;
  const float4* x4 = (const float4*)x + (size_t)nc * 4096;
  float4 sa = {0.f, 0.f, 0.f, 0.f};
  for (int i = 0; i < 16; ++i) {
    int s = w * 16 + i;
    float4 v = x4[(size_t)s * 64 + l];
    sa.x += v.x; sa.y += v.y; sa.z += v.z; sa.w += v.w;
    float ds = v.x + v.y + v.z + v.w;
    #pragma unroll
    for (int off = 32; off; off >>= 1) ds += __shfl_down(ds, off, 64);
    if (l == 0) desc_t[((size_t)n * 64 + s) * 256 + c] = ds * (1.f / 256.f);
  }
  __shared__ float4 lsp[4][64];
  lsp[w][l] = sa;
  __syncthreads();
  if (t < 64) {
    float4 a = lsp[0][t], b = lsp[1][t], c2 = lsp[2][t], d = lsp[3][t];
    float4 tot;
    tot.x = a.x + b.x + c2.x + d.x; tot.y = a.y + b.y + c2.y + d.y;
    tot.z = a.z + b.z + c2.z + d.z; tot.w = a.w + b.w + c2.w + d.w;
    size_t base = ((size_t)n * 256 + t * 4) * 256 + c;
    sp_t[base]       = tot.x * (1.f / 64.f);
    sp_t[base + 256] = tot.y * (1.f / 64.f);
    sp_t[base + 512] = tot.z * (1.f / 64.f);
    sp_t[base + 768] = tot.w * (1.f / 64.f);
  }
}

// ---------------- LayerNorm over C per (n,s) ----------------
__global__ __launch_bounds__(256) void ln_kernel(
    const float* __restrict__ desc_t, const float* __restrict__ g,
    const float* __restrict__ b, float* __restrict__ dn_t) {
  __shared__ float sc[4];
  int col = blockIdx.x; int t = threadIdx.x;
  float v = desc_t[(size_t)col * 256 + t];
  float s1 = block_sum256(v, sc);
  float s2 = block_sum256(v * v, sc);
  float mu = s1 * (1.f / 256.f);
  float var = s2 * (1.f / 256.f) - mu * mu;
  float r = rsqrtf(var + 1e-5f);
  dn_t[(size_t)col * 256 + t] = (v - mu) * r * g[t] + b[t];
}

// ---------------- diffs + staging buffers (gib/moi/bpi) ----------------
__global__ __launch_bounds__(256) void prep_mi_kernel(
    const float* __restrict__ dn_t,
    float* __restrict__ gib, float* __restrict__ moi, float* __restrict__ bpi) {
  int col = blockIdx.x; int c = threadIdx.x;
  int s = col & 63;
  float d = dn_t[(size_t)col * 256 + c];
  float d1 = (s >= 1) ? d - dn_t[(size_t)(col - 1) * 256 + c] : 0.f;
  gib[(size_t)col * 512 + c] = d;
  gib[(size_t)col * 512 + 256 + c] = fabsf(d1);
  moi[(size_t)col * 768 + c] = d;
  bpi[(size_t)col * 1024 + c] = d;
}

// ---------------- rFFT over S (direct DFT) ----------------
__global__ __launch_bounds__(256) void fft_kernel(
    const float* __restrict__ dn_t, float* __restrict__ fe,
    float* __restrict__ mfre, float* __restrict__ mfim) {
  int b = blockIdx.x; int n = b / 33; int f = b % 33;
  int t = threadIdx.x;
  __shared__ float cs[64], sn[64];
  __shared__ float sc[4];
  if (t < 64) {
    int ft = (f * t) & 63;
    float ang = -6.283185307179586f * (float)ft * (1.f / 64.f);
    cs[t] = cosf(ang); sn[t] = sinf(ang);
  }
  __syncthreads();
  float re = 0.f, im = 0.f;
  const float* base = dn_t + (size_t)n * 16384 + t;
  for (int s = 0; s < 64; ++s) {
    float v = base[(size_t)s * 256];
    re += v * cs[s]; im += v * sn[s];
  }
  re *= 0.125f; im *= 0.125f;   // ortho 1/sqrt(64)
  float mag = sqrtf(re * re + im * im);
  float sm = block_sum256(mag, sc);
  float sr = block_sum256(re, sc);
  float si = block_sum256(im, sc);
  if (t == 0) {
    fe[b]   = sm * (1.f / 256.f);
    mfre[b] = sr * (1.f / 256.f);
    mfim[b] = si * (1.f / 256.f);
  }
}

// ---------------- peak / phase params per n ----------------
__global__ __launch_bounds__(64) void peak_kernel(
    const float* __restrict__ fe, const float* __restrict__ mfre,
    const float* __restrict__ mfim, float* __restrict__ pk) {
  int n = blockIdx.x; int t = threadIdx.x;
  float v = (t < 26) ? fe[n * 33 + 7 + t] : -1e30f;
  int idx = t;
  float hs = (t < 26) ? v : 0.f;
  #pragma unroll
  for (int off = 32; off; off >>= 1) {
    float ov = __shfl_down(v, off, 64);
    int   oi = __shfl_down(idx, off, 64);
    float oh = __shfl_down(hs, off, 64);
    hs += oh;
    if (ov > v || (ov == v && oi < idx)) { v = ov; idx = oi; }
  }
  if (t == 0) {
    int pi = idx + 7;
    float conf = v / fmaxf(hs, 1e-6f);
    float pnorm = (float)pi * (1.f / 32.f);
    float re = mfre[n * 33 + pi], im = mfim[n * 33 + pi];
    float dph = atan2f(im, re);
    float ang = (6.283185307179586f / 64.f) * (float)pi;
    pk[n * 4 + 0] = conf; pk[n * 4 + 1] = pnorm; pk[n * 4 + 2] = dph; pk[n * 4 + 3] = ang;
  }
}

// ---------------- generic 1x1-conv GEMM: 1 col/wave, grid (4, cols/4) ----------------
// EPI: 0 = gelu(v*sc+bi); 1 = sigmoid(v+bi); 2 = none; 3 = v*fg[col][o]*rs[o]; 4 = sigmoid(v*sc+bi)
template <int K, int EPI>
__global__ __launch_bounds__(256) void gemm_kernel(
    const float* __restrict__ At, const float* __restrict__ B, float* __restrict__ out,
    const float* __restrict__ sc, const float* __restrict__ bi,
    const float* __restrict__ fg, const float* __restrict__ rs) {
  int t = threadIdx.x;
  int o = blockIdx.x * 64 + (t & 63);
  int col = blockIdx.y * 4 + (t >> 6);
  const float* bp = B + (size_t)col * K;
  float4 a0 = {0.f,0.f,0.f,0.f};
  for (int kk = 0; kk < K; kk += 4) {
    float4 b0 = *(const float4*)(bp + kk);
    a0.x += At[(size_t)(kk + 0) * 256 + o] * b0.x;
    a0.y += At[(size_t)(kk + 1) * 256 + o] * b0.y;
    a0.z += At[(size_t)(kk + 2) * 256 + o] * b0.z;
    a0.w += At[(size_t)(kk + 3) * 256 + o] * b0.w;
  }
  float v0 = (a0.x + a0.y) + (a0.z + a0.w);
  if constexpr (EPI == 0) { v0 = gelu_f(v0 * sc[o] + bi[o]); }
  else if constexpr (EPI == 1) { v0 = sigmoid_f(v0 + bi[o]); }
  else if constexpr (EPI == 3) { v0 *= fg[(size_t)col * 256 + o] * rs[o]; }
  else if constexpr (EPI == 4) { v0 = sigmoid_f(v0 * sc[o] + bi[o]); }
  out[(size_t)col * 256 + o] = v0;
}

// ---------------- gated fwd/bwd scan over S (LDS-staged) ----------------
__global__ __launch_bounds__(256) void scan_kernel(
    const float* __restrict__ dn_t, const float* __restrict__ gate_t, float* __restrict__ moi) {
  int n = blockIdx.x, half = blockIdx.y;
  int t = threadIdx.x;
  __shared__ float ld[64 * 128];
  __shared__ float lg[64 * 128];
  const float* dsrc = dn_t + (size_t)n * 16384 + half * 128;
  const float* gsrc = gate_t + (size_t)n * 16384 + half * 128;
  for (int i = t; i < 8192; i += 256) {
    int s = i >> 7, j = i & 127;
    ld[i] = dsrc[(size_t)s * 256 + j];
    lg[i] = gsrc[(size_t)s * 256 + j];
  }
  __syncthreads();
  int cl = t & 127;
  int c = half * 128 + cl;
  size_t ob = (size_t)n * 64 * 768 + c;
  if (t < 128) {
    float st = ld[cl];
    moi[ob + 256] = st;
    for (int s = 1; s < 64; ++s) {
      float g = lg[s * 128 + cl], d = ld[s * 128 + cl];
      st = g * st + (1.f - g) * d;
      moi[ob + (size_t)s * 768 + 256] = st;
    }
  } else {
    float st = ld[63 * 128 + cl];
    moi[ob + (size_t)63 * 768 + 512] = st;
    for (int s = 62; s >= 0; --s) {
      float g = lg[s * 128 + cl], d = ld[s * 128 + cl];
      st = g * st + (1.f - g) * d;
      moi[ob + (size_t)s * 768 + 512] = st;
    }
  }
}

// ---------------- phase gate ----------------
__global__ __launch_bounds__(256) void pgate_kernel(
    const float* __restrict__ dn_t, const float* __restrict__ pk,
    const float* __restrict__ pg_w1, const float* __restrict__ pg_s1, const float* __restrict__ pg_b1,
    const float* __restrict__ pg_w2, const float* __restrict__ pg_b2, float* __restrict__ ppin) {
  int col = blockIdx.x; int n = col >> 6; int s = col & 63;
  int t = threadIdx.x;
  __shared__ float h[64];
  float conf = pk[n * 4 + 0], dph = pk[n * 4 + 2], ang = pk[n * 4 + 3];
  float arg = ang * (float)s + dph;
  float pc = cosf(arg), ps = sinf(arg);
  if (t < 64) {
    float v = pg_w1[t * 3 + 0] * pc + pg_w1[t * 3 + 1] * ps + pg_w1[t * 3 + 2] * conf;
    v = v * pg_s1[t] + pg_b1[t];
    h[t] = gelu_f(v);
  }
  __syncthreads();
  float acc = pg_b2[t];
  const float* wrow = pg_w2 + t * 64;
  #pragma unroll 8
  for (int j = 0; j < 64; ++j) acc += wrow[j] * h[j];
  float pg = sigmoid_f(acc);
  ppin[(size_t)col * 256 + t] = dn_t[(size_t)col * 256 + t] * pg;
}

// ---------------- router ----------------
__global__ __launch_bounds__(256) void router_kernel(
    const float* __restrict__ dn_t, const float* __restrict__ motion_t,
    const float* __restrict__ memory_t, const float* __restrict__ pk,
    const float* __restrict__ rt_w1, const float* __restrict__ rt_b1,
    const float* __restrict__ rt_w2, const float* __restrict__ rt_b2,
    float* __restrict__ bw) {
  int n = blockIdx.x; int c = threadIdx.x;
  __shared__ float ri[261];
  __shared__ float h2[64];
  __shared__ float lg[3];
  __shared__ float sc[4];
  float sum = 0.f, sq = 0.f, ad1 = 0.f, amot = 0.f, amem = 0.f, prev = 0.f;
  for (int s = 0; s < 64; ++s) {
    size_t i = ((size_t)n * 64 + s) * 256 + c;
    float d = dn_t[i];
    sum += d; sq += d * d;
    if (s > 0) ad1 += fabsf(d - prev);
    prev = d;
    amot += fabsf(motion_t[i]);
    amem += fabsf(memory_t[i] - d);
  }
  float mean = sum * (1.f / 64.f);
  float var = sq * (1.f / 64.f) - mean * mean;
  float stdc = sqrtf(fmaxf(var, 0.f));
  ri[c] = mean;
  float rstd = block_sum256(stdc, sc);
  float rad1 = block_sum256(ad1, sc);
  float rmot = block_sum256(amot, sc);
  float rmem = block_sum256(amem, sc);
  if (c == 0) {
    ri[256] = rstd * (1.f / 256.f);
    ri[257] = rad1 * (1.f / 16384.f);
    ri[258] = pk[n * 4 + 0];
    ri[259] = pk[n * 4 + 1];
    ri[260] = (rmem + rmot) * (1.f / 16384.f);
  }
  __syncthreads();
  if (c < 64) {
    float acc = rt_b1[c];
    const float* wrow = rt_w1 + c * 261;
    for (int i = 0; i < 261; ++i) acc += wrow[i] * ri[i];
    h2[c] = gelu_f(acc);
  }
  __syncthreads();
  if (c < 3) {
    float acc = rt_b2[c];
    const float* wrow = rt_w2 + c * 64;
    #pragma unroll 8
    for (int j = 0; j < 64; ++j) acc += wrow[j] * h2[j];
    lg[c] = acc;
  }
  __syncthreads();
  if (c == 0) {
    float m = fmaxf(lg[0], fmaxf(lg[1], lg[2]));
    float e0 = expf(lg[0] - m), e1 = expf(lg[1] - m), e2 = expf(lg[2] - m);
    float inv = 1.f / (e0 + e1 + e2);
    bw[n * 3 + 0] = e0 * inv; bw[n * 3 + 1] = e1 * inv; bw[n * 3 + 2] = e2 * inv;
  }
}

// ---------------- build bp input rows 256..1023 ----------------
__global__ __launch_bounds__(256) void bp_prep_kernel(
    const float* __restrict__ motion_t, const float* __restrict__ phase_t,
    const float* __restrict__ memory_t, const float* __restrict__ dn_t,
    const float* __restrict__ bw, float* __restrict__ bpi) {
  int col = blockIdx.x; int c = threadIdx.x; int n = col >> 6;
  size_t i = (size_t)col * 256 + c;
  float m = motion_t[i], p = phase_t[i], me = memory_t[i], d = dn_t[i];
  float b0 = bw[n * 3 + 0], b1 = bw[n * 3 + 1], b2 = bw[n * 3 + 2];
  size_t base = (size_t)col * 1024;
  bpi[base + 256 + c] = b0 * m + b1 * p + b2 * me;
  bpi[base + 512 + c] = m - p;
  bpi[base + 768 + c] = me - d;
}

// ---------------- pass 2: out = x + delta * sgate ----------------
__global__ __launch_bounds__(256) void final_kernel(
    const float* __restrict__ x, const float* __restrict__ delta_t,
    const float* __restrict__ sgate_t, float* __restrict__ out) {
  int nc = blockIdx.x; int n = nc >> 8; int c = nc & 255;
  int t = threadIdx.x;
  __shared__ float dlt[64];
  __shared__ float4 sgs4[64];
  if (t < 64) dlt[t] = delta_t[((size_t)n * 64 + t) * 256 + c];
  ((float*)sgs4)[t] = sgate_t[((size_t)n * 256 + t) * 256 + c];
  __syncthreads();
  const float4* x4 = (const float4*)x + (size_t)nc * 4096;
  float4* o4 = (float4*)out + (size_t)nc * 4096;
  int w = t >> 6, l = t & 63;
  float4 sg = sgs4[l];
  for (int i = 0; i < 16; ++i) {
    int s = w * 16 + i;
    float d = dlt[s];
    float4 v = x4[(size_t)s * 64 + l];
    v.x += d * sg.x; v.y += d * sg.y; v.z += d * sg.z; v.w += d * sg.w;
    o4[(size_t)s * 64 + l] = v;
  }
}

} // namespace

extern "C" void kernel_launch(void* const* d_in, const int* in_sizes, int n_in,
                              void* d_out, int out_size, void* d_ws, size_t ws_size,
                              hipStream_t stream) {
  const float* x      = (const float*)d_in[0];
  const float* ln_g   = (const float*)d_in[1];
  const float* ln_b   = (const float*)d_in[2];
  const float* mb_w3  = (const float*)d_in[3];
  const float* mb_s3  = (const float*)d_in[4];
  const float* mb_b3  = (const float*)d_in[5];
  const float* mb_w5  = (const float*)d_in[6];
  const float* mb_s5  = (const float*)d_in[7];
  const float* mb_b5  = (const float*)d_in[8];
  const float* mb_w7  = (const float*)d_in[9];
  const float* mb_s7  = (const float*)d_in[10];
  const float* mb_b7  = (const float*)d_in[11];
  const float* mf_w   = (const float*)d_in[12];
  const float* mf_s   = (const float*)d_in[13];
  const float* mf_b   = (const float*)d_in[14];
  const float* pg_w1  = (const float*)d_in[15];
  const float* pg_s1  = (const float*)d_in[16];
  const float* pg_b1  = (const float*)d_in[17];
  const float* pg_w2  = (const float*)d_in[18];
  const float* pg_b2  = (const float*)d_in[19];
  const float* pp_w   = (const float*)d_in[20];
  const float* pp_s   = (const float*)d_in[21];
  const float* pp_b   = (const float*)d_in[22];
  const float* mg_w   = (const float*)d_in[23];
  const float* mg_b   = (const float*)d_in[24];
  const float* mo_w1  = (const float*)d_in[25];
  const float* mo_s1  = (const float*)d_in[26];
  const float* mo_b1  = (const float*)d_in[27];
  const float* mo_w2  = (const float*)d_in[28];
  const float* rt_w1  = (const float*)d_in[29];
  const float* rt_b1  = (const float*)d_in[30];
  const float* rt_w2  = (const float*)d_in[31];
  const float* rt_b2  = (const float*)d_in[32];
  const float* bp_w1  = (const float*)d_in[33];
  const float* bp_s1  = (const float*)d_in[34];
  const float* bp_b1  = (const float*)d_in[35];
  const float* bp_w2  = (const float*)d_in[36];
  const float* res_sc = (const float*)d_in[37];
  const float* fg_w   = (const float*)d_in[38];
  const float* fg_b   = (const float*)d_in[39];
  const float* sg_w   = (const float*)d_in[40];
  const float* sg_s   = (const float*)d_in[41];
  const float* sg_b   = (const float*)d_in[42];
  float* ws = (float*)d_ws;
  float* out = (float*)d_out;
  unsigned short* wfrag = (unsigned short*)(ws + O_WFRAG);
  unsigned short* im2   = (unsigned short*)(ws + O_IM2);

  transpose_kernel<<<dim3(120, 8), 256, 0, stream>>>(mf_w, mg_w, mo_w1, mo_w2,
      pp_w, bp_w1, bp_w2, fg_w, sg_w, ws);
  wfrag_kernel<<<2016, 256, 0, stream>>>(mb_w3, mb_w5, mb_w7, wfrag);
  reduce_x_kernel<<<2048, 256, 0, stream>>>(x, ws + O_DESC, ws + O_SPT);
  ln_kernel<<<512, 256, 0, stream>>>(ws + O_DESC, ln_g, ln_b, ws + O_DN);
  im2col_kernel<<<1344, 256, 0, stream>>>(ws + O_DN, im2);
  prep_mi_kernel<<<512, 256, 0, stream>>>(ws + O_DN, ws + O_GIB, ws + O_MOI, ws + O_BPI);
  fft_kernel<<<264, 256, 0, stream>>>(ws + O_DN, ws + O_FE, ws + O_MFRE, ws + O_MFIM);
  peak_kernel<<<8, 64, 0, stream>>>(ws + O_FE, ws + O_MFRE, ws + O_MFIM, ws + O_PK);
  conv_mfma_kernel<<<dim3(12, 8, 4), 256, 0, stream>>>(wfrag, im2, ws + O_CONVC);
  combine_kernel<<<dim3(16, 8), 256, 0, stream>>>(ws + O_CONVC, mb_s3, mb_b3, mb_s5, mb_b5, mb_s7, mb_b7, ws + O_MSUM);
  gemm_kernel<256, 0><<<dim3(4, 128), 256, 0, stream>>>(ws + O_ATMF, ws + O_MSUM, ws + O_MOT, mf_s, mf_b, nullptr, nullptr);
  gemm_kernel<512, 1><<<dim3(4, 128), 256, 0, stream>>>(ws + O_ATMG, ws + O_GIB, ws + O_GATE, nullptr, mg_b, nullptr, nullptr);
  scan_kernel<<<dim3(8, 2), 256, 0, stream>>>(ws + O_DN, ws + O_GATE, ws + O_MOI);
  gemm_kernel<768, 0><<<dim3(4, 128), 256, 0, stream>>>(ws + O_ATMO1, ws + O_MOI, ws + O_HMO, mo_s1, mo_b1, nullptr, nullptr);
  gemm_kernel<256, 2><<<dim3(4, 128), 256, 0, stream>>>(ws + O_ATMO2, ws + O_HMO, ws + O_MEM, nullptr, nullptr, nullptr, nullptr);
  pgate_kernel<<<512, 256, 0, stream>>>(ws + O_DN, ws + O_PK, pg_w1, pg_s1, pg_b1, pg_w2, pg_b2, ws + O_PPIN);
  gemm_kernel<256, 0><<<dim3(4, 128), 256, 0, stream>>>(ws + O_ATPP, ws + O_PPIN, ws + O_PHASE, pp_s, pp_b, nullptr, nullptr);
  gemm_kernel<256, 1><<<dim3(4, 128), 256, 0, stream>>>(ws + O_ATFG, ws + O_DN, ws + O_FGATE, nullptr, fg_b, nullptr, nullptr);
  router_kernel<<<8, 256, 0, stream>>>(ws + O_DN, ws + O_MOT, ws + O_MEM, ws + O_PK,
      rt_w1, rt_b1, rt_w2, rt_b2, ws + O_BW);
  bp_prep_kernel<<<512, 256, 0, stream>>>(ws + O_MOT, ws + O_PHASE, ws + O_MEM, ws + O_DN, ws + O_BW, ws + O_BPI);
  gemm_kernel<1024, 0><<<dim3(4, 128), 256, 0, stream>>>(ws + O_ATBP1, ws + O_BPI, ws + O_HBP, bp_s1, bp_b1, nullptr, nullptr);
  gemm_kernel<256, 3><<<dim3(4, 128), 256, 0, stream>>>(ws + O_ATBP2, ws + O_HBP, ws + O_DELTA, nullptr, nullptr, ws + O_FGATE, res_sc);
  gemm_kernel<256, 4><<<dim3(4, 512), 256, 0, stream>>>(ws + O_ATSG, ws + O_SPT, ws + O_SGATE, sg_s, sg_b, nullptr, nullptr);
  final_kernel<<<2048, 256, 0, stream>>>(x, ws + O_DELTA, ws + O_SGATE, out);
}